// Round 6
// baseline (222.016 us; speedup 1.0000x reference)
//
#include <hip/hip_runtime.h>
#include <hip/hip_fp16.h>

// KbInterpForw: table-based KB NUFFT interpolation, forward.
// x: (2,16,2,512,512) f32, om: (2,2,262144) f32, tables: (2,6145) f32 each.
// out: (2,16,2,262144) f32.
//
// R12 (on R11's 221.7 us):
//  - interp LDS layout: drop the per-record pad (TQ 5 -> 4 float4), keep a
//    row-level pad (row stride 85 f4). Record base phase = (20*row+16*col)
//    mod 32 -- same 8 bank-phase classes as R11, but LDS 35.3 -> 28.5 KB ->
//    5 blocks/CU (20 waves, +25% latency hiding). Kernel is issue/latency
//    bound (R6 vs R10 evidence), so waves convert to wall time.
//  - hist2d / scatter2 at 1024 threads/block (grid still 256 = 1 block/CU):
//    16 waves/CU instead of 4. scatter2's scattered 8 B som writes + strided
//    blockHist gathers are latency-dominated with no TLP at 4 waves.
//    Rank-within-(block,bin) order changes; inv[] records the actual
//    permutation so output is unchanged.

#define KLEN      262144      // 2^18
#define GX        512
#define GY        512
#define NCOILS    16
#define NBATCH    2
#define TBL_LEN   6145        // 6*1024+1
#define TBL_CTR   3072
#define PLANE     (GX*GY)
#define NPTS      (NBATCH*KLEN)
#define NBINS     2048        // NBATCH * 32*32 tiles
#define NBLK      256         // sort blocks
#define PPB       2048        // points per sort block (NPTS/NBLK)

#define TROWS     21          // 16 + 5 halo
#define RST       85          // float4 per tile row (21*4 + 1 pad)

typedef _Float16 half2_t __attribute__((ext_vector_type(2)));
struct alignas(16) H8 { half2_t h[4]; };   // 4 coils' (re,im) fp16 = 16 B

// ---------------------------------------------------------------------------
// ws layout (bytes). blockHist aliases osort (dead before interp writes
// osort). btot lives in the unaliased gap: interp reads it at block start
// while other blocks may already be writing osort.
// ---------------------------------------------------------------------------
#define WS_XT       0                         // 33554432  fp16 grid records
#define WS_OSORT    33554432                  // 33554432  fp16 sorted outputs
#define WS_BHIST    33554432                  //  2097152  u32 [NBINS][NBLK] (alias osort)
#define WS_BTOT     67108864                  //     8192  u32 [NBINS]  NOT aliased
#define WS_INV      69206016                  //  2097152  u32 pos per point id
#define WS_SOM      71303168                  //  4194304  float2 om per pos
#define WS_TOTAL    75497472

__device__ inline int point_bin(float om0, float om1)
{
    const float TWO_PI = 6.2831853071795864769f;
    const float tm0 = (om0 * 512.0f) / TWO_PI;
    const float tm1 = (om1 * 512.0f) / TWO_PI;
    const int cx = ((int)floorf(tm0)) & 511;
    const int cy = ((int)floorf(tm1)) & 511;
    return ((cx >> 4) << 5) | (cy >> 4);      // [0, 1024)
}

// quad broadcast: every lane receives lane (quadbase+O)'s value. VALU op,
// stays off the LDS pipe. Only called from fully-active quads.
template<int O>
__device__ inline half2_t qbc(half2_t v)
{
    int i;
    __builtin_memcpy(&i, &v, 4);
    i = __builtin_amdgcn_mov_dpp(i, (O | (O << 2) | (O << 4) | (O << 6)),
                                 0xf, 0xf, true);
    half2_t r;
    __builtin_memcpy(&r, &i, 4);
    return r;
}

// ---------------------------------------------------------------------------
// Transpose+downconvert via LDS. Block handles 256 consecutive cells.
// ---------------------------------------------------------------------------
__global__ __launch_bounds__(256) void transpose_fp16(
    const float* __restrict__ x, float4* __restrict__ xt)
{
    __shared__ float s[32][260];   // [plane][cell], pad 260 (16B-aligned rows)
    const int blk   = blockIdx.x;            // [0, NBATCH*PLANE/256)
    const int base  = blk * 256;
    const int b     = base >> 18;
    const int cell0 = base & (PLANE - 1);
    const int t     = threadIdx.x;

    const float* xb = x + (size_t)b * 32 * PLANE + cell0;
#pragma unroll
    for (int i = 0; i < 8; ++i) {
        const int fidx = i * 256 + t;        // [0, 2048)
        const int pl = fidx >> 6;            // wave-uniform plane
        const int j  = fidx & 63;
        const float4 v = *(const float4*)(xb + (size_t)pl * PLANE + j * 4);
        *(float4*)&s[pl][j * 4] = v;
    }
    __syncthreads();
#pragma unroll
    for (int i = 0; i < 4; ++i) {
        const int chunk = i * 256 + t;       // [0, 1024)
        const int cell = chunk >> 2, q = chunk & 3;
        H8 rec;
#pragma unroll
        for (int cc = 0; cc < 4; ++cc) {
            const int c = q * 4 + cc;
            rec.h[cc] = half2_t{(_Float16)s[2 * c][cell],
                                (_Float16)s[2 * c + 1][cell]};
        }
        xt[((size_t)b * PLANE + cell0 + cell) * 4 + q] = *(const float4*)&rec;
    }
}

// ---------------------------------------------------------------------------
// Sort pass 1: per-block LDS histogram -> blockHist[bin][blk] (bin-major).
// 1024 threads (16 waves/CU) for latency hiding; grid stays NBLK.
// ---------------------------------------------------------------------------
__global__ __launch_bounds__(1024) void hist2d(
    const float* __restrict__ om, unsigned* __restrict__ blockHist)
{
    __shared__ unsigned h[NBINS];
    const int t = threadIdx.x, blk = blockIdx.x;
#pragma unroll
    for (int i = 0; i < NBINS / 1024; ++i) h[t + i * 1024] = 0u;
    __syncthreads();
#pragma unroll
    for (int i = 0; i < PPB / 1024; ++i) {
        const int id = blk * PPB + i * 1024 + t;
        const int b = id >> 18, m = id & (KLEN - 1);
        const float om0 = om[(size_t)(b * 2 + 0) * KLEN + m];
        const float om1 = om[(size_t)(b * 2 + 1) * KLEN + m];
        const int g = (b << 10) | point_bin(om0, om1);
        atomicAdd(&h[g], 1u);
    }
    __syncthreads();
#pragma unroll
    for (int i = 0; i < NBINS / 1024; ++i) {
        const int bin = t + i * 1024;
        blockHist[(size_t)bin * NBLK + blk] = h[bin];   // strided once
    }
}

// ---------------------------------------------------------------------------
// Sort pass 2: per-bin exclusive scan over NBLK block counts + per-bin total.
// ---------------------------------------------------------------------------
__global__ __launch_bounds__(256) void scan_bins(
    unsigned* __restrict__ blockHist, unsigned* __restrict__ binTotal)
{
    __shared__ unsigned partial[256];
    const int bin = blockIdx.x;
    const int t = threadIdx.x;
    const unsigned v = blockHist[(size_t)bin * NBLK + t];   // coalesced 1 KB
    partial[t] = v;
    __syncthreads();
    for (int d = 1; d < 256; d <<= 1) {
        unsigned x = (t >= d) ? partial[t - d] : 0u;
        __syncthreads();
        partial[t] += x;
        __syncthreads();
    }
    blockHist[(size_t)bin * NBLK + t] = partial[t] - v;     // exclusive
    if (t == 255) binTotal[bin] = partial[255];
}

// ---------------------------------------------------------------------------
// Sort pass 3: final positions. In-block LDS scan of btot gives bin bases;
// LDS atomics give local rank within (block, bin). 1024 threads.
// ---------------------------------------------------------------------------
__global__ __launch_bounds__(1024) void scatter2(
    const float*    __restrict__ om,
    const unsigned* __restrict__ blockHist,
    const unsigned* __restrict__ btot,
    unsigned* __restrict__ inv,
    float2* __restrict__ som)
{
    __shared__ unsigned h[NBINS];
    __shared__ unsigned bbs[NBINS];
    __shared__ unsigned part[1024];
    const int t = threadIdx.x, blk = blockIdx.x;

    // exclusive scan of btot -> bbs (redundant per block; btot is L2-hot)
    unsigned v[2];
    unsigned s = 0;
#pragma unroll
    for (int i = 0; i < 2; ++i) { v[i] = btot[t * 2 + i]; s += v[i]; }
    part[t] = s;
#pragma unroll
    for (int i = 0; i < NBINS / 1024; ++i) h[t + i * 1024] = 0u;
    __syncthreads();
    for (int d = 1; d < 1024; d <<= 1) {
        unsigned x = (t >= d) ? part[t - d] : 0u;
        __syncthreads();
        part[t] += x;
        __syncthreads();
    }
    unsigned base = (t > 0) ? part[t - 1] : 0u;
    bbs[t * 2]     = base;
    bbs[t * 2 + 1] = base + v[0];
    __syncthreads();

#pragma unroll
    for (int i = 0; i < PPB / 1024; ++i) {
        const int id = blk * PPB + i * 1024 + t;
        const int b = id >> 18, m = id & (KLEN - 1);
        const float om0 = om[(size_t)(b * 2 + 0) * KLEN + m];
        const float om1 = om[(size_t)(b * 2 + 1) * KLEN + m];
        const int g = (b << 10) | point_bin(om0, om1);
        const unsigned r = atomicAdd(&h[g], 1u);
        const unsigned pos = bbs[g] + blockHist[(size_t)g * NBLK + blk] + r;
        inv[id]  = pos;
        som[pos] = make_float2(om0, om1);
    }
}

// ---------------------------------------------------------------------------
// Main interp: ONE BLOCK PER BIN. Stage the bin's 21x21-record halo tile
// into LDS: record stride 4 f4 (64 B, no pad), row stride RST=85 f4 (row
// pad keeps 8 bank-phase classes; LDS 28.5 KB -> 5 blocks/CU). All gathers
// are ds_read_b128. 4 lanes/point; coefficient pairs DPP-quad-shared.
// ---------------------------------------------------------------------------
__global__ __launch_bounds__(256) void interp_bins(
    const float2*   __restrict__ som,
    const float*    __restrict__ t0,
    const float*    __restrict__ t1,
    const float4*   __restrict__ xt,
    const unsigned* __restrict__ btot,
    float4*         __restrict__ osort)
{
    __shared__ float4 tile[TROWS * RST];          // 1785 f4 = 28560 B
    const int bin = blockIdx.x;
    const int t   = threadIdx.x;
    const int b   = bin >> 10;
    const int cx0 = ((bin >> 5) & 31) << 4;
    const int cy0 = (bin & 31) << 4;

    // ---- bin range via in-block exclusive scan of btot (aliases tile) ---
    unsigned p0, p1e;
    {
        unsigned* sb = (unsigned*)tile;           // [0..2047] scan, [2048..] partial
        unsigned v[8];
        unsigned s = 0;
#pragma unroll
        for (int i = 0; i < 8; ++i) { v[i] = btot[t * 8 + i]; s += v[i]; }
        sb[NBINS + t] = s;
        __syncthreads();
        for (int d = 1; d < 256; d <<= 1) {
            unsigned x = (t >= d) ? sb[NBINS + t - d] : 0u;
            __syncthreads();
            sb[NBINS + t] += x;
            __syncthreads();
        }
        unsigned base = (t > 0) ? sb[NBINS + t - 1] : 0u;
#pragma unroll
        for (int i = 0; i < 8; ++i) { sb[t * 8 + i] = base; base += v[i]; }
        __syncthreads();
        p0  = sb[bin];
        p1e = (bin == NBINS - 1) ? (unsigned)NPTS : sb[bin + 1];
        __syncthreads();   // done with sb before tile overwrite
    }
    const int cnt = (int)(p1e - p0);

    // ---- stage halo tile: 441 records x 4 chunks, coalesced rows --------
    const float4* rec = xt + ((size_t)b << 20);   // b * PLANE * 4 chunks
    for (int f = t; f < TROWS * TROWS * 4; f += 256) {
        const int r = f >> 2, q = f & 3;
        const int row = r / TROWS;                // const-div -> magic mul
        const int col = r - row * TROWS;
        const int gr = (cx0 - 2 + row) & 511;
        const int gc = (cy0 - 2 + col) & 511;
        tile[row * RST + col * 4 + q] = rec[(((size_t)((gr << 9) | gc)) << 2) + q];
    }
    __syncthreads();

    const int lane = t & 3;
    for (int base = 0; base < cnt; base += 64) {
        const int idx = base + (t >> 2);
        if (idx >= cnt) continue;                 // whole quad skips together
        const int pos = (int)p0 + idx;

        const float2 o = som[pos];
        const float om0 = o.x, om1 = o.y;

        const float TWO_PI = 6.2831853071795864769f;
        const float tm0 = (om0 * 512.0f) / TWO_PI;
        const float tm1 = (om1 * 512.0f) / TWO_PI;

        const float koff0 = 1.0f + floorf(tm0 - 3.0f);
        const float koff1 = 1.0f + floorf(tm1 - 3.0f);
        const int   k0    = (int)koff0;
        const int   k1    = (int)koff1;

        // c0: all 6, every lane (outer factor). c1: only this lane's j1s.
        float c0r[6], c0i[6];
        int   loff[6];
#pragma unroll
        for (int j = 0; j < 6; ++j) {
            const float g0 = koff0 + (float)j;
            const int   d0 = (int)rintf((tm0 - g0) * 1024.0f) + TBL_CTR;
            c0r[j] = t0[d0];
            c0i[j] = t0[TBL_LEN + d0];
            loff[j] = ((k1 + j - cy0 + 2) & 511) * 4;    // in [0, 20]*4
        }
        const int j1a = lane;                       // pair A owner: lane j1
        const int j1b = (lane < 2) ? lane + 4 : lane;   // pair B (lanes 0,1)
        const int d1a = (int)rintf((tm1 - (koff1 + (float)j1a)) * 1024.0f) + TBL_CTR;
        const int d1b = (int)rintf((tm1 - (koff1 + (float)j1b)) * 1024.0f) + TBL_CTR;
        const float c1ra = t1[d1a], c1ia = t1[TBL_LEN + d1a];
        const float c1rb = t1[d1b], c1ib = t1[TBL_LEN + d1b];

        float acr[4] = {0.f, 0.f, 0.f, 0.f};
        float aci[4] = {0.f, 0.f, 0.f, 0.f};

#define KB_DO_J1(JJ, OWNER, PP1, PP2)                                         \
        do {                                                                  \
            const half2_t p1 = qbc<OWNER>(PP1);                               \
            const half2_t p2 = qbc<OWNER>(PP2);                               \
            const float4 raw = rowp[loff[JJ]];                                \
            const H8 v = *(const H8*)&raw;                                    \
            _Pragma("unroll")                                                 \
            for (int cc = 0; cc < 4; ++cc) {                                  \
                acr[cc] = __builtin_amdgcn_fdot2(v.h[cc], p1, acr[cc], false);\
                aci[cc] = __builtin_amdgcn_fdot2(v.h[cc], p2, aci[cc], false);\
            }                                                                 \
        } while (0)

#pragma unroll
        for (int j0 = 0; j0 < 6; ++j0) {
            const int rIdx = (k0 + j0 - cx0 + 2) & 511;  // in [0, 20]
            const float4* rowp = &tile[rIdx * RST + lane];
            const float ar = c0r[j0], ai = c0i[j0];
            // this lane's pairs (same f32 math every lane ran before R11)
            const float crA = ar * c1ra - ai * c1ia;
            const float ciA = ar * c1ia + ai * c1ra;
            const float crB = ar * c1rb - ai * c1ib;
            const float ciB = ar * c1ib + ai * c1rb;
            const half2_t pA1 = {(_Float16)crA, (_Float16)(-ciA)};
            const half2_t pA2 = {(_Float16)ciA, (_Float16)crA};
            const half2_t pB1 = {(_Float16)crB, (_Float16)(-ciB)};
            const half2_t pB2 = {(_Float16)ciB, (_Float16)crB};

            KB_DO_J1(0, 0, pA1, pA2);
            KB_DO_J1(1, 1, pA1, pA2);
            KB_DO_J1(2, 2, pA1, pA2);
            KB_DO_J1(3, 3, pA1, pA2);
            KB_DO_J1(4, 0, pB1, pB2);
            KB_DO_J1(5, 1, pB1, pB2);
        }
#undef KB_DO_J1

        // phase twist: exp(i * (om0+om1)*128); |ph| <= 128 rev -> native ok
        const float ph = om0 * 128.0f + om1 * 128.0f;
        const float s = __sinf(ph), c = __cosf(ph);

        H8 outrec;
#pragma unroll
        for (int cc = 0; cc < 4; ++cc) {
            const float yr = acr[cc] * c - aci[cc] * s;
            const float yi = acr[cc] * s + aci[cc] * c;
            outrec.h[cc] = half2_t{(_Float16)yr, (_Float16)yi};
        }
        osort[(size_t)pos * 4 + lane] = *(const float4*)&outrec;   // coalesced
    }
}

// ---------------------------------------------------------------------------
// Unsort: thread per point id; gather 64 B record from osort, store coalesced
// into final (b,c,ri,m) layout.
// ---------------------------------------------------------------------------
__global__ __launch_bounds__(256) void unsort_kernel(
    const unsigned* __restrict__ inv,
    const float4*   __restrict__ osort,
    float*          __restrict__ out)
{
    const int id = blockIdx.x * blockDim.x + threadIdx.x;   // [0, NPTS)
    const int b = id >> 18, m = id & (KLEN - 1);
    const unsigned pos = inv[id];
    const float4* rp = osort + (size_t)pos * 4;

    float4 raw[4];
#pragma unroll
    for (int q = 0; q < 4; ++q) raw[q] = rp[q];

    float* ob = out + (size_t)b * NCOILS * 2 * KLEN + m;
#pragma unroll
    for (int q = 0; q < 4; ++q) {
        const H8 v = *(const H8*)&raw[q];
#pragma unroll
        for (int cc = 0; cc < 4; ++cc) {
            const int coil = q * 4 + cc;
            ob[(size_t)(2 * coil)     * KLEN] = (float)v.h[cc].x;
            ob[(size_t)(2 * coil + 1) * KLEN] = (float)v.h[cc].y;
        }
    }
}

// ---------------------------------------------------------------------------
// Middle path (ws >= xt only): direct-order interp (4 lanes/point).
// ---------------------------------------------------------------------------
__global__ __launch_bounds__(256) void interp_direct(
    const float*  __restrict__ om,
    const float*  __restrict__ t0,
    const float*  __restrict__ t1,
    const float4* __restrict__ xt,
    float*        __restrict__ out)
{
    const int tid  = blockIdx.x * blockDim.x + threadIdx.x;
    const int lane = tid & 3;
    const int p    = tid >> 2;
    const int b    = p >> 18;
    const int m    = p & (KLEN - 1);

    const float om0 = om[(size_t)(b * 2 + 0) * KLEN + m];
    const float om1 = om[(size_t)(b * 2 + 1) * KLEN + m];

    const float TWO_PI = 6.2831853071795864769f;
    const float tm0 = (om0 * 512.0f) / TWO_PI;
    const float tm1 = (om1 * 512.0f) / TWO_PI;
    const float koff0 = 1.0f + floorf(tm0 - 3.0f);
    const float koff1 = 1.0f + floorf(tm1 - 3.0f);
    const int k0 = (int)koff0, k1 = (int)koff1;

    float c0r[6], c0i[6], c1r[6], c1i[6];
    int coff[6];
#pragma unroll
    for (int j = 0; j < 6; ++j) {
        const float g0 = koff0 + (float)j;
        const int d0 = (int)rintf((tm0 - g0) * 1024.0f) + TBL_CTR;
        c0r[j] = t0[d0];
        c0i[j] = t0[TBL_LEN + d0];
        const float g1 = koff1 + (float)j;
        const int d1 = (int)rintf((tm1 - g1) * 1024.0f) + TBL_CTR;
        c1r[j] = t1[d1];
        c1i[j] = t1[TBL_LEN + d1];
        coff[j] = ((k1 + j) & 511) << 2;
    }

    const float4* rec = xt + ((size_t)b << 20);
    float acr[4] = {0.f, 0.f, 0.f, 0.f};
    float aci[4] = {0.f, 0.f, 0.f, 0.f};
#pragma unroll
    for (int j0 = 0; j0 < 6; ++j0) {
        const int roff = (k0 + j0) & 511;
        const float4* rowp = rec + ((size_t)roff << 11) + lane;
        const float ar = c0r[j0], ai = c0i[j0];
#pragma unroll
        for (int j1 = 0; j1 < 6; ++j1) {
            const float br = c1r[j1], bi = c1i[j1];
            const float cr = ar * br - ai * bi;
            const float ci = ar * bi + ai * br;
            const half2_t p1 = {(_Float16)cr, (_Float16)(-ci)};
            const half2_t p2 = {(_Float16)ci, (_Float16)cr};
            const float4 raw = rowp[coff[j1]];
            const H8 v = *(const H8*)&raw;
#pragma unroll
            for (int cc = 0; cc < 4; ++cc) {
                acr[cc] = __builtin_amdgcn_fdot2(v.h[cc], p1, acr[cc], false);
                aci[cc] = __builtin_amdgcn_fdot2(v.h[cc], p2, aci[cc], false);
            }
        }
    }

    const float ph = om0 * 128.0f + om1 * 128.0f;
    const float s = sinf(ph), c = cosf(ph);
#pragma unroll
    for (int cc = 0; cc < 4; ++cc) {
        const float yr = acr[cc] * c - aci[cc] * s;
        const float yi = acr[cc] * s + aci[cc] * c;
        const int coil = lane * 4 + cc;
        const size_t ob = ((size_t)(b * NCOILS + coil) * 2) * KLEN + m;
        out[ob]        = yr;
        out[ob + KLEN] = yi;
    }
}

// ---------------------------------------------------------------------------
// Fallback (tiny ws): one thread per point, original layout.
// ---------------------------------------------------------------------------
__global__ __launch_bounds__(256) void interp_fallback(
    const float* __restrict__ om,
    const float* __restrict__ t0,
    const float* __restrict__ t1,
    const float* __restrict__ x,
    float*       __restrict__ out)
{
    const int p = blockIdx.x * blockDim.x + threadIdx.x;
    const int b = p >> 18;
    const int m = p & (KLEN - 1);

    const float om0 = om[(size_t)(b * 2 + 0) * KLEN + m];
    const float om1 = om[(size_t)(b * 2 + 1) * KLEN + m];
    const float TWO_PI = 6.2831853071795864769f;
    const float tm0 = (om0 * 512.0f) / TWO_PI;
    const float tm1 = (om1 * 512.0f) / TWO_PI;
    const float koff0 = 1.0f + floorf(tm0 - 3.0f);
    const float koff1 = 1.0f + floorf(tm1 - 3.0f);
    const int k0 = (int)koff0, k1 = (int)koff1;

    float c0r[6], c0i[6], c1r[6], c1i[6];
    int roff[6], coff[6];
#pragma unroll
    for (int j = 0; j < 6; ++j) {
        const float g0 = koff0 + (float)j;
        const int d0 = (int)rintf((tm0 - g0) * 1024.0f) + TBL_CTR;
        c0r[j] = t0[d0];
        c0i[j] = t0[TBL_LEN + d0];
        const float g1 = koff1 + (float)j;
        const int d1 = (int)rintf((tm1 - g1) * 1024.0f) + TBL_CTR;
        c1r[j] = t1[d1];
        c1i[j] = t1[TBL_LEN + d1];
        roff[j] = (k0 + j) & 511;
        coff[j] = (k1 + j) & 511;
    }

    float accr[NCOILS], acci[NCOILS];
#pragma unroll
    for (int c = 0; c < NCOILS; ++c) { accr[c] = 0.f; acci[c] = 0.f; }

    const float* xb = x + (size_t)b * NCOILS * 2 * PLANE;
#pragma unroll
    for (int j0 = 0; j0 < 6; ++j0) {
        const float ar = c0r[j0], ai = c0i[j0];
        const int rb = roff[j0] * GY;
#pragma unroll
        for (int j1 = 0; j1 < 6; ++j1) {
            const float br = c1r[j1], bi = c1i[j1];
            const float cr = ar * br - ai * bi;
            const float ci = ar * bi + ai * br;
            const int ai_idx = rb + coff[j1];
#pragma unroll
            for (int c = 0; c < NCOILS; ++c) {
                const float dr = xb[(size_t)c * (2 * PLANE) + ai_idx];
                const float di = xb[(size_t)c * (2 * PLANE) + PLANE + ai_idx];
                accr[c] += cr * dr - ci * di;
                acci[c] += cr * di + ci * dr;
            }
        }
    }

    const float ph = om0 * 128.0f + om1 * 128.0f;
    const float s = sinf(ph), c = cosf(ph);
#pragma unroll
    for (int cc = 0; cc < NCOILS; ++cc) {
        const float yr = accr[cc] * c - acci[cc] * s;
        const float yi = accr[cc] * s + acci[cc] * c;
        size_t ob = ((size_t)(b * NCOILS + cc) * 2) * KLEN + m;
        out[ob]        = yr;
        out[ob + KLEN] = yi;
    }
}

extern "C" void kernel_launch(void* const* d_in, const int* in_sizes, int n_in,
                              void* d_out, int out_size, void* d_ws, size_t ws_size,
                              hipStream_t stream)
{
    const float* x  = (const float*)d_in[0];
    const float* om = (const float*)d_in[1];
    const float* t0 = (const float*)d_in[2];
    const float* t1 = (const float*)d_in[3];
    float* out = (float*)d_out;

    char* ws = (char*)d_ws;
    const size_t xt_bytes = (size_t)NBATCH * PLANE * NCOILS * 2 * sizeof(__half);

    if (ws_size >= (size_t)WS_TOTAL) {
        float4*   xt     = (float4*)(ws + WS_XT);
        float4*   osort  = (float4*)(ws + WS_OSORT);
        unsigned* bhist  = (unsigned*)(ws + WS_BHIST);
        unsigned* btot   = (unsigned*)(ws + WS_BTOT);
        unsigned* inv    = (unsigned*)(ws + WS_INV);
        float2*   som    = (float2*)(ws + WS_SOM);

        transpose_fp16<<<NBATCH * PLANE / 256, 256, 0, stream>>>(x, xt);
        hist2d<<<NBLK, 1024, 0, stream>>>(om, bhist);
        scan_bins<<<NBINS, 256, 0, stream>>>(bhist, btot);
        scatter2<<<NBLK, 1024, 0, stream>>>(om, bhist, btot, inv, som);
        interp_bins<<<NBINS, 256, 0, stream>>>(som, t0, t1, xt, btot, osort);
        unsort_kernel<<<NPTS / 256, 256, 0, stream>>>(inv, osort, out);
    } else if (ws_size >= xt_bytes) {
        float4* xt = (float4*)ws;
        transpose_fp16<<<NBATCH * PLANE / 256, 256, 0, stream>>>(x, xt);
        interp_direct<<<NPTS * 4 / 256, 256, 0, stream>>>(om, t0, t1, xt, out);
    } else {
        interp_fallback<<<NPTS / 256, 256, 0, stream>>>(om, t0, t1, x, out);
    }
}

// Round 7
// 219.747 us; speedup vs baseline: 1.0103x; 1.0103x over previous
//
#include <hip/hip_runtime.h>
#include <hip/hip_fp16.h>

// KbInterpForw: table-based KB NUFFT interpolation, forward.
// x: (2,16,2,512,512) f32, om: (2,2,262144) f32, tables: (2,6145) f32 each.
// out: (2,16,2,262144) f32.
//
// R13 (on R12's 222 us):
//  - interp LDS tile reverted to R11's proven TQ=5 record-pad layout (R12's
//    row-pad layout regressed 64.7 -> 71.4 us despite higher occupancy).
//  - interp no longer scans btot: scatter2's block 0 publishes the bin-base
//    array to global bbase; interp reads bbase[bin] / bbase[bin+1] (2 loads).
//    Deletes a 2048-element LDS scan (+16 barriers) from each of the 2048
//    interp blocks.
//  - transpose_fp16 and hist2d fused into one dispatch via block-range split
//    (disjoint inputs, no dependency; hist latency hides under the BW-bound
//    transpose; one launch gap saved). 5 dispatches total.
//  - 1024-thread scatter2 kept (R12 win). Deterministic sort throughout.

#define KLEN      262144      // 2^18
#define GX        512
#define GY        512
#define NCOILS    16
#define NBATCH    2
#define TBL_LEN   6145        // 6*1024+1
#define TBL_CTR   3072
#define PLANE     (GX*GY)
#define NPTS      (NBATCH*KLEN)
#define NBINS     2048        // NBATCH * 32*32 tiles
#define NBLK      256         // sort blocks
#define PPB       2048        // points per sort block (NPTS/NBLK)
#define TBLKS     (NBATCH*PLANE/256)   // 2048 transpose blocks... (8192)

#define TROWS     21          // 16 + 5 halo
#define TQ        5           // float4 slots per record in LDS (4 used + 1 pad)

typedef _Float16 half2_t __attribute__((ext_vector_type(2)));
struct alignas(16) H8 { half2_t h[4]; };   // 4 coils' (re,im) fp16 = 16 B

// ---------------------------------------------------------------------------
// ws layout (bytes). blockHist aliases osort (dead before interp writes
// osort). btot/bbase live in the unaliased gap after osort.
// ---------------------------------------------------------------------------
#define WS_XT       0                         // 33554432  fp16 grid records
#define WS_OSORT    33554432                  // 33554432  fp16 sorted outputs
#define WS_BHIST    33554432                  //  2097152  u32 [NBINS][NBLK] (alias osort)
#define WS_BTOT     67108864                  //     8192  u32 [NBINS]  NOT aliased
#define WS_BBASE    (67108864+8192)           //     8192  u32 [NBINS]  NOT aliased
#define WS_INV      69206016                  //  2097152  u32 pos per point id
#define WS_SOM      71303168                  //  4194304  float2 om per pos
#define WS_TOTAL    75497472

__device__ inline int point_bin(float om0, float om1)
{
    const float TWO_PI = 6.2831853071795864769f;
    const float tm0 = (om0 * 512.0f) / TWO_PI;
    const float tm1 = (om1 * 512.0f) / TWO_PI;
    const int cx = ((int)floorf(tm0)) & 511;
    const int cy = ((int)floorf(tm1)) & 511;
    return ((cx >> 4) << 5) | (cy >> 4);      // [0, 1024)
}

// quad broadcast: every lane receives lane (quadbase+O)'s value. VALU op,
// stays off the LDS pipe. Only called from fully-active quads.
template<int O>
__device__ inline half2_t qbc(half2_t v)
{
    int i;
    __builtin_memcpy(&i, &v, 4);
    i = __builtin_amdgcn_mov_dpp(i, (O | (O << 2) | (O << 4) | (O << 6)),
                                 0xf, 0xf, true);
    half2_t r;
    __builtin_memcpy(&r, &i, 4);
    return r;
}

// ---------------------------------------------------------------------------
// Fused transpose+hist. Blocks [0, TBLKS): transpose 256 consecutive cells
// via LDS. Blocks [TBLKS, TBLKS+NBLK): per-block LDS histogram ->
// blockHist[bin][blk] (bin-major). Pass blockHist=nullptr (grid=TBLKS) to
// run transpose only (middle path).
// ---------------------------------------------------------------------------
__global__ __launch_bounds__(256) void transpose_hist(
    const float* __restrict__ x, float4* __restrict__ xt,
    const float* __restrict__ om, unsigned* __restrict__ blockHist)
{
    __shared__ float s[32][260];   // 33280 B; hist aliases first 8192 B
    const int t = threadIdx.x;

    if (blockHist != nullptr && blockIdx.x >= TBLKS) {
        // ---- histogram body (256 threads, 8 iters) ----------------------
        unsigned* h = (unsigned*)s;               // [NBINS]
        const int blk = blockIdx.x - TBLKS;
#pragma unroll
        for (int i = 0; i < NBINS / 256; ++i) h[t + i * 256] = 0u;
        __syncthreads();
#pragma unroll
        for (int i = 0; i < PPB / 256; ++i) {
            const int id = blk * PPB + i * 256 + t;
            const int b = id >> 18, m = id & (KLEN - 1);
            const float om0 = om[(size_t)(b * 2 + 0) * KLEN + m];
            const float om1 = om[(size_t)(b * 2 + 1) * KLEN + m];
            const int g = (b << 10) | point_bin(om0, om1);
            atomicAdd(&h[g], 1u);
        }
        __syncthreads();
#pragma unroll
        for (int i = 0; i < NBINS / 256; ++i) {
            const int bin = t + i * 256;
            blockHist[(size_t)bin * NBLK + blk] = h[bin];   // strided once
        }
        return;
    }

    // ---- transpose body -------------------------------------------------
    const int blk   = blockIdx.x;            // [0, TBLKS)
    const int base  = blk * 256;
    const int b     = base >> 18;
    const int cell0 = base & (PLANE - 1);

    const float* xb = x + (size_t)b * 32 * PLANE + cell0;
#pragma unroll
    for (int i = 0; i < 8; ++i) {
        const int fidx = i * 256 + t;        // [0, 2048)
        const int pl = fidx >> 6;            // wave-uniform plane
        const int j  = fidx & 63;
        const float4 v = *(const float4*)(xb + (size_t)pl * PLANE + j * 4);
        *(float4*)&s[pl][j * 4] = v;
    }
    __syncthreads();
#pragma unroll
    for (int i = 0; i < 4; ++i) {
        const int chunk = i * 256 + t;       // [0, 1024)
        const int cell = chunk >> 2, q = chunk & 3;
        H8 rec;
#pragma unroll
        for (int cc = 0; cc < 4; ++cc) {
            const int c = q * 4 + cc;
            rec.h[cc] = half2_t{(_Float16)s[2 * c][cell],
                                (_Float16)s[2 * c + 1][cell]};
        }
        xt[((size_t)b * PLANE + cell0 + cell) * 4 + q] = *(const float4*)&rec;
    }
}

// ---------------------------------------------------------------------------
// Sort pass 2: per-bin exclusive scan over NBLK block counts + per-bin total.
// ---------------------------------------------------------------------------
__global__ __launch_bounds__(256) void scan_bins(
    unsigned* __restrict__ blockHist, unsigned* __restrict__ binTotal)
{
    __shared__ unsigned partial[256];
    const int bin = blockIdx.x;
    const int t = threadIdx.x;
    const unsigned v = blockHist[(size_t)bin * NBLK + t];   // coalesced 1 KB
    partial[t] = v;
    __syncthreads();
    for (int d = 1; d < 256; d <<= 1) {
        unsigned x = (t >= d) ? partial[t - d] : 0u;
        __syncthreads();
        partial[t] += x;
        __syncthreads();
    }
    blockHist[(size_t)bin * NBLK + t] = partial[t] - v;     // exclusive
    if (t == 255) binTotal[bin] = partial[255];
}

// ---------------------------------------------------------------------------
// Sort pass 3: final positions. In-block LDS scan of btot gives bin bases
// (block 0 publishes them to global bbase for interp); LDS atomics give
// local rank within (block, bin). 1024 threads.
// ---------------------------------------------------------------------------
__global__ __launch_bounds__(1024) void scatter2(
    const float*    __restrict__ om,
    const unsigned* __restrict__ blockHist,
    const unsigned* __restrict__ btot,
    unsigned* __restrict__ bbase,
    unsigned* __restrict__ inv,
    float2* __restrict__ som)
{
    __shared__ unsigned h[NBINS];
    __shared__ unsigned bbs[NBINS];
    __shared__ unsigned part[1024];
    const int t = threadIdx.x, blk = blockIdx.x;

    // exclusive scan of btot -> bbs (redundant per block; btot is L2-hot)
    unsigned v[2];
    unsigned s = 0;
#pragma unroll
    for (int i = 0; i < 2; ++i) { v[i] = btot[t * 2 + i]; s += v[i]; }
    part[t] = s;
#pragma unroll
    for (int i = 0; i < NBINS / 1024; ++i) h[t + i * 1024] = 0u;
    __syncthreads();
    for (int d = 1; d < 1024; d <<= 1) {
        unsigned x = (t >= d) ? part[t - d] : 0u;
        __syncthreads();
        part[t] += x;
        __syncthreads();
    }
    unsigned base = (t > 0) ? part[t - 1] : 0u;
    bbs[t * 2]     = base;
    bbs[t * 2 + 1] = base + v[0];
    if (blk == 0) {                           // publish for interp_bins
        bbase[t * 2]     = base;
        bbase[t * 2 + 1] = base + v[0];
    }
    __syncthreads();

#pragma unroll
    for (int i = 0; i < PPB / 1024; ++i) {
        const int id = blk * PPB + i * 1024 + t;
        const int b = id >> 18, m = id & (KLEN - 1);
        const float om0 = om[(size_t)(b * 2 + 0) * KLEN + m];
        const float om1 = om[(size_t)(b * 2 + 1) * KLEN + m];
        const int g = (b << 10) | point_bin(om0, om1);
        const unsigned r = atomicAdd(&h[g], 1u);
        const unsigned pos = bbs[g] + blockHist[(size_t)g * NBLK + blk] + r;
        inv[id]  = pos;
        som[pos] = make_float2(om0, om1);
    }
}

// ---------------------------------------------------------------------------
// Main interp: ONE BLOCK PER BIN. Stage the bin's 21x21-record halo tile
// into LDS (stride TQ=5 float4 per record -> period-8 bank phases; R11's
// proven layout). All gathers are ds_read_b128. 4 lanes/point; coefficient
// pairs DPP-quad-shared. Bin range from precomputed bbase (2 loads).
// ---------------------------------------------------------------------------
__global__ __launch_bounds__(256) void interp_bins(
    const float2*   __restrict__ som,
    const float*    __restrict__ t0,
    const float*    __restrict__ t1,
    const float4*   __restrict__ xt,
    const unsigned* __restrict__ bbase,
    float4*         __restrict__ osort)
{
    __shared__ float4 tile[TROWS * TROWS * TQ];   // 2205 f4 = 35280 B
    const int bin = blockIdx.x;
    const int t   = threadIdx.x;
    const int b   = bin >> 10;
    const int cx0 = ((bin >> 5) & 31) << 4;
    const int cy0 = (bin & 31) << 4;

    const unsigned p0  = bbase[bin];
    const unsigned p1e = (bin == NBINS - 1) ? (unsigned)NPTS : bbase[bin + 1];
    const int cnt = (int)(p1e - p0);

    // ---- stage halo tile: 441 records x 4 chunks, coalesced rows --------
    const float4* rec = xt + ((size_t)b << 20);   // b * PLANE * 4 chunks
    for (int f = t; f < TROWS * TROWS * 4; f += 256) {
        const int r = f >> 2, q = f & 3;
        const int row = r / TROWS;                // const-div -> magic mul
        const int col = r - row * TROWS;
        const int gr = (cx0 - 2 + row) & 511;
        const int gc = (cy0 - 2 + col) & 511;
        tile[r * TQ + q] = rec[(((size_t)((gr << 9) | gc)) << 2) + q];
    }
    __syncthreads();

    const int lane = t & 3;
    for (int base = 0; base < cnt; base += 64) {
        const int idx = base + (t >> 2);
        if (idx >= cnt) continue;                 // whole quad skips together
        const int pos = (int)p0 + idx;

        const float2 o = som[pos];
        const float om0 = o.x, om1 = o.y;

        const float TWO_PI = 6.2831853071795864769f;
        const float tm0 = (om0 * 512.0f) / TWO_PI;
        const float tm1 = (om1 * 512.0f) / TWO_PI;

        const float koff0 = 1.0f + floorf(tm0 - 3.0f);
        const float koff1 = 1.0f + floorf(tm1 - 3.0f);
        const int   k0    = (int)koff0;
        const int   k1    = (int)koff1;

        // c0: all 6, every lane (outer factor). c1: only this lane's j1s.
        float c0r[6], c0i[6];
        int   loff[6];
#pragma unroll
        for (int j = 0; j < 6; ++j) {
            const float g0 = koff0 + (float)j;
            const int   d0 = (int)rintf((tm0 - g0) * 1024.0f) + TBL_CTR;
            c0r[j] = t0[d0];
            c0i[j] = t0[TBL_LEN + d0];
            loff[j] = ((k1 + j - cy0 + 2) & 511) * TQ;   // in [0, 20]*TQ
        }
        const int j1a = lane;                       // pair A owner: lane j1
        const int j1b = (lane < 2) ? lane + 4 : lane;   // pair B (lanes 0,1)
        const int d1a = (int)rintf((tm1 - (koff1 + (float)j1a)) * 1024.0f) + TBL_CTR;
        const int d1b = (int)rintf((tm1 - (koff1 + (float)j1b)) * 1024.0f) + TBL_CTR;
        const float c1ra = t1[d1a], c1ia = t1[TBL_LEN + d1a];
        const float c1rb = t1[d1b], c1ib = t1[TBL_LEN + d1b];

        float acr[4] = {0.f, 0.f, 0.f, 0.f};
        float aci[4] = {0.f, 0.f, 0.f, 0.f};

#define KB_DO_J1(JJ, OWNER, PP1, PP2)                                         \
        do {                                                                  \
            const half2_t p1 = qbc<OWNER>(PP1);                               \
            const half2_t p2 = qbc<OWNER>(PP2);                               \
            const float4 raw = rowp[loff[JJ]];                                \
            const H8 v = *(const H8*)&raw;                                    \
            _Pragma("unroll")                                                 \
            for (int cc = 0; cc < 4; ++cc) {                                  \
                acr[cc] = __builtin_amdgcn_fdot2(v.h[cc], p1, acr[cc], false);\
                aci[cc] = __builtin_amdgcn_fdot2(v.h[cc], p2, aci[cc], false);\
            }                                                                 \
        } while (0)

#pragma unroll
        for (int j0 = 0; j0 < 6; ++j0) {
            const int rIdx = (k0 + j0 - cx0 + 2) & 511;  // in [0, 20]
            const float4* rowp = &tile[rIdx * (TROWS * TQ) + lane];
            const float ar = c0r[j0], ai = c0i[j0];
            // this lane's pairs (same f32 math every lane ran pre-R11)
            const float crA = ar * c1ra - ai * c1ia;
            const float ciA = ar * c1ia + ai * c1ra;
            const float crB = ar * c1rb - ai * c1ib;
            const float ciB = ar * c1ib + ai * c1rb;
            const half2_t pA1 = {(_Float16)crA, (_Float16)(-ciA)};
            const half2_t pA2 = {(_Float16)ciA, (_Float16)crA};
            const half2_t pB1 = {(_Float16)crB, (_Float16)(-ciB)};
            const half2_t pB2 = {(_Float16)ciB, (_Float16)crB};

            KB_DO_J1(0, 0, pA1, pA2);
            KB_DO_J1(1, 1, pA1, pA2);
            KB_DO_J1(2, 2, pA1, pA2);
            KB_DO_J1(3, 3, pA1, pA2);
            KB_DO_J1(4, 0, pB1, pB2);
            KB_DO_J1(5, 1, pB1, pB2);
        }
#undef KB_DO_J1

        // phase twist: exp(i * (om0+om1)*128); |ph| <= 128 rev -> native ok
        const float ph = om0 * 128.0f + om1 * 128.0f;
        const float s = __sinf(ph), c = __cosf(ph);

        H8 outrec;
#pragma unroll
        for (int cc = 0; cc < 4; ++cc) {
            const float yr = acr[cc] * c - aci[cc] * s;
            const float yi = acr[cc] * s + aci[cc] * c;
            outrec.h[cc] = half2_t{(_Float16)yr, (_Float16)yi};
        }
        osort[(size_t)pos * 4 + lane] = *(const float4*)&outrec;   // coalesced
    }
}

// ---------------------------------------------------------------------------
// Unsort: thread per point id; gather 64 B record from osort, store coalesced
// into final (b,c,ri,m) layout.
// ---------------------------------------------------------------------------
__global__ __launch_bounds__(256) void unsort_kernel(
    const unsigned* __restrict__ inv,
    const float4*   __restrict__ osort,
    float*          __restrict__ out)
{
    const int id = blockIdx.x * blockDim.x + threadIdx.x;   // [0, NPTS)
    const int b = id >> 18, m = id & (KLEN - 1);
    const unsigned pos = inv[id];
    const float4* rp = osort + (size_t)pos * 4;

    float4 raw[4];
#pragma unroll
    for (int q = 0; q < 4; ++q) raw[q] = rp[q];

    float* ob = out + (size_t)b * NCOILS * 2 * KLEN + m;
#pragma unroll
    for (int q = 0; q < 4; ++q) {
        const H8 v = *(const H8*)&raw[q];
#pragma unroll
        for (int cc = 0; cc < 4; ++cc) {
            const int coil = q * 4 + cc;
            ob[(size_t)(2 * coil)     * KLEN] = (float)v.h[cc].x;
            ob[(size_t)(2 * coil + 1) * KLEN] = (float)v.h[cc].y;
        }
    }
}

// ---------------------------------------------------------------------------
// Middle path (ws >= xt only): direct-order interp (4 lanes/point).
// ---------------------------------------------------------------------------
__global__ __launch_bounds__(256) void interp_direct(
    const float*  __restrict__ om,
    const float*  __restrict__ t0,
    const float*  __restrict__ t1,
    const float4* __restrict__ xt,
    float*        __restrict__ out)
{
    const int tid  = blockIdx.x * blockDim.x + threadIdx.x;
    const int lane = tid & 3;
    const int p    = tid >> 2;
    const int b    = p >> 18;
    const int m    = p & (KLEN - 1);

    const float om0 = om[(size_t)(b * 2 + 0) * KLEN + m];
    const float om1 = om[(size_t)(b * 2 + 1) * KLEN + m];

    const float TWO_PI = 6.2831853071795864769f;
    const float tm0 = (om0 * 512.0f) / TWO_PI;
    const float tm1 = (om1 * 512.0f) / TWO_PI;
    const float koff0 = 1.0f + floorf(tm0 - 3.0f);
    const float koff1 = 1.0f + floorf(tm1 - 3.0f);
    const int k0 = (int)koff0, k1 = (int)koff1;

    float c0r[6], c0i[6], c1r[6], c1i[6];
    int coff[6];
#pragma unroll
    for (int j = 0; j < 6; ++j) {
        const float g0 = koff0 + (float)j;
        const int d0 = (int)rintf((tm0 - g0) * 1024.0f) + TBL_CTR;
        c0r[j] = t0[d0];
        c0i[j] = t0[TBL_LEN + d0];
        const float g1 = koff1 + (float)j;
        const int d1 = (int)rintf((tm1 - g1) * 1024.0f) + TBL_CTR;
        c1r[j] = t1[d1];
        c1i[j] = t1[TBL_LEN + d1];
        coff[j] = ((k1 + j) & 511) << 2;
    }

    const float4* rec = xt + ((size_t)b << 20);
    float acr[4] = {0.f, 0.f, 0.f, 0.f};
    float aci[4] = {0.f, 0.f, 0.f, 0.f};
#pragma unroll
    for (int j0 = 0; j0 < 6; ++j0) {
        const int roff = (k0 + j0) & 511;
        const float4* rowp = rec + ((size_t)roff << 11) + lane;
        const float ar = c0r[j0], ai = c0i[j0];
#pragma unroll
        for (int j1 = 0; j1 < 6; ++j1) {
            const float br = c1r[j1], bi = c1i[j1];
            const float cr = ar * br - ai * bi;
            const float ci = ar * bi + ai * br;
            const half2_t p1 = {(_Float16)cr, (_Float16)(-ci)};
            const half2_t p2 = {(_Float16)ci, (_Float16)cr};
            const float4 raw = rowp[coff[j1]];
            const H8 v = *(const H8*)&raw;
#pragma unroll
            for (int cc = 0; cc < 4; ++cc) {
                acr[cc] = __builtin_amdgcn_fdot2(v.h[cc], p1, acr[cc], false);
                aci[cc] = __builtin_amdgcn_fdot2(v.h[cc], p2, aci[cc], false);
            }
        }
    }

    const float ph = om0 * 128.0f + om1 * 128.0f;
    const float s = sinf(ph), c = cosf(ph);
#pragma unroll
    for (int cc = 0; cc < 4; ++cc) {
        const float yr = acr[cc] * c - aci[cc] * s;
        const float yi = acr[cc] * s + aci[cc] * c;
        const int coil = lane * 4 + cc;
        const size_t ob = ((size_t)(b * NCOILS + coil) * 2) * KLEN + m;
        out[ob]        = yr;
        out[ob + KLEN] = yi;
    }
}

// ---------------------------------------------------------------------------
// Fallback (tiny ws): one thread per point, original layout.
// ---------------------------------------------------------------------------
__global__ __launch_bounds__(256) void interp_fallback(
    const float* __restrict__ om,
    const float* __restrict__ t0,
    const float* __restrict__ t1,
    const float* __restrict__ x,
    float*       __restrict__ out)
{
    const int p = blockIdx.x * blockDim.x + threadIdx.x;
    const int b = p >> 18;
    const int m = p & (KLEN - 1);

    const float om0 = om[(size_t)(b * 2 + 0) * KLEN + m];
    const float om1 = om[(size_t)(b * 2 + 1) * KLEN + m];
    const float TWO_PI = 6.2831853071795864769f;
    const float tm0 = (om0 * 512.0f) / TWO_PI;
    const float tm1 = (om1 * 512.0f) / TWO_PI;
    const float koff0 = 1.0f + floorf(tm0 - 3.0f);
    const float koff1 = 1.0f + floorf(tm1 - 3.0f);
    const int k0 = (int)koff0, k1 = (int)koff1;

    float c0r[6], c0i[6], c1r[6], c1i[6];
    int roff[6], coff[6];
#pragma unroll
    for (int j = 0; j < 6; ++j) {
        const float g0 = koff0 + (float)j;
        const int d0 = (int)rintf((tm0 - g0) * 1024.0f) + TBL_CTR;
        c0r[j] = t0[d0];
        c0i[j] = t0[TBL_LEN + d0];
        const float g1 = koff1 + (float)j;
        const int d1 = (int)rintf((tm1 - g1) * 1024.0f) + TBL_CTR;
        c1r[j] = t1[d1];
        c1i[j] = t1[TBL_LEN + d1];
        roff[j] = (k0 + j) & 511;
        coff[j] = (k1 + j) & 511;
    }

    float accr[NCOILS], acci[NCOILS];
#pragma unroll
    for (int c = 0; c < NCOILS; ++c) { accr[c] = 0.f; acci[c] = 0.f; }

    const float* xb = x + (size_t)b * NCOILS * 2 * PLANE;
#pragma unroll
    for (int j0 = 0; j0 < 6; ++j0) {
        const float ar = c0r[j0], ai = c0i[j0];
        const int rb = roff[j0] * GY;
#pragma unroll
        for (int j1 = 0; j1 < 6; ++j1) {
            const float br = c1r[j1], bi = c1i[j1];
            const float cr = ar * br - ai * bi;
            const float ci = ar * bi + ai * br;
            const int ai_idx = rb + coff[j1];
#pragma unroll
            for (int c = 0; c < NCOILS; ++c) {
                const float dr = xb[(size_t)c * (2 * PLANE) + ai_idx];
                const float di = xb[(size_t)c * (2 * PLANE) + PLANE + ai_idx];
                accr[c] += cr * dr - ci * di;
                acci[c] += cr * di + ci * dr;
            }
        }
    }

    const float ph = om0 * 128.0f + om1 * 128.0f;
    const float s = sinf(ph), c = cosf(ph);
#pragma unroll
    for (int cc = 0; cc < NCOILS; ++cc) {
        const float yr = accr[cc] * c - acci[cc] * s;
        const float yi = accr[cc] * s + acci[cc] * c;
        size_t ob = ((size_t)(b * NCOILS + cc) * 2) * KLEN + m;
        out[ob]        = yr;
        out[ob + KLEN] = yi;
    }
}

extern "C" void kernel_launch(void* const* d_in, const int* in_sizes, int n_in,
                              void* d_out, int out_size, void* d_ws, size_t ws_size,
                              hipStream_t stream)
{
    const float* x  = (const float*)d_in[0];
    const float* om = (const float*)d_in[1];
    const float* t0 = (const float*)d_in[2];
    const float* t1 = (const float*)d_in[3];
    float* out = (float*)d_out;

    char* ws = (char*)d_ws;
    const size_t xt_bytes = (size_t)NBATCH * PLANE * NCOILS * 2 * sizeof(__half);

    if (ws_size >= (size_t)WS_TOTAL) {
        float4*   xt     = (float4*)(ws + WS_XT);
        float4*   osort  = (float4*)(ws + WS_OSORT);
        unsigned* bhist  = (unsigned*)(ws + WS_BHIST);
        unsigned* btot   = (unsigned*)(ws + WS_BTOT);
        unsigned* bbase  = (unsigned*)(ws + WS_BBASE);
        unsigned* inv    = (unsigned*)(ws + WS_INV);
        float2*   som    = (float2*)(ws + WS_SOM);

        transpose_hist<<<TBLKS + NBLK, 256, 0, stream>>>(x, xt, om, bhist);
        scan_bins<<<NBINS, 256, 0, stream>>>(bhist, btot);
        scatter2<<<NBLK, 1024, 0, stream>>>(om, bhist, btot, bbase, inv, som);
        interp_bins<<<NBINS, 256, 0, stream>>>(som, t0, t1, xt, bbase, osort);
        unsort_kernel<<<NPTS / 256, 256, 0, stream>>>(inv, osort, out);
    } else if (ws_size >= xt_bytes) {
        float4* xt = (float4*)ws;
        transpose_hist<<<TBLKS, 256, 0, stream>>>(x, xt, om, nullptr);
        interp_direct<<<NPTS * 4 / 256, 256, 0, stream>>>(om, t0, t1, xt, out);
    } else {
        interp_fallback<<<NPTS / 256, 256, 0, stream>>>(om, t0, t1, x, out);
    }
}

// Round 8
// 212.474 us; speedup vs baseline: 1.0449x; 1.0342x over previous
//
#include <hip/hip_runtime.h>
#include <hip/hip_fp16.h>

// KbInterpForw: table-based KB NUFFT interpolation, forward.
// x: (2,16,2,512,512) f32, om: (2,2,262144) f32, tables: (2,6145) f32 each.
// out: (2,16,2,262144) f32.
//
// R14 (on R13's 219.7 us):
//  - interp_bins at 512 threads/block (was 256). LDS 35.3 KB allows 4
//    resident blocks/CU either way, but 512-thread blocks carry 8 waves each
//    -> 32 waves/CU (100% cap) vs 16. VGPR=52 <= 64 so 8 waves/SIMD is
//    legal. Kernel shows 40% latency gaps (VALU 59% busy, occ 29%) -- waves
//    convert to wall time. Tile layout (proven TQ=5) untouched.
//  - scan_bins rewritten wave-per-bin: 128 blocks x 1024 thr, each wave
//    scans one bin's 256 counts via __shfl_up (6 steps, ZERO barriers) vs
//    2048 blocks x 16-round barrier ladders.
//  - scatter2 preamble scan wave-based: 6 shfl steps + 1 barrier vs 10
//    rounds x 3 barriers. Same exclusive-scan values (deterministic).

#define KLEN      262144      // 2^18
#define GX        512
#define GY        512
#define NCOILS    16
#define NBATCH    2
#define TBL_LEN   6145        // 6*1024+1
#define TBL_CTR   3072
#define PLANE     (GX*GY)
#define NPTS      (NBATCH*KLEN)
#define NBINS     2048        // NBATCH * 32*32 tiles
#define NBLK      256         // sort blocks
#define PPB       2048        // points per sort block (NPTS/NBLK)
#define TBLKS     (NBATCH*PLANE/256)   // 8192 transpose blocks

#define TROWS     21          // 16 + 5 halo
#define TQ        5           // float4 slots per record in LDS (4 used + 1 pad)

typedef _Float16 half2_t __attribute__((ext_vector_type(2)));
struct alignas(16) H8 { half2_t h[4]; };   // 4 coils' (re,im) fp16 = 16 B

// ---------------------------------------------------------------------------
// ws layout (bytes). blockHist aliases osort (dead before interp writes
// osort). btot/bbase live in the unaliased gap after osort.
// ---------------------------------------------------------------------------
#define WS_XT       0                         // 33554432  fp16 grid records
#define WS_OSORT    33554432                  // 33554432  fp16 sorted outputs
#define WS_BHIST    33554432                  //  2097152  u32 [NBINS][NBLK] (alias osort)
#define WS_BTOT     67108864                  //     8192  u32 [NBINS]  NOT aliased
#define WS_BBASE    (67108864+8192)           //     8192  u32 [NBINS]  NOT aliased
#define WS_INV      69206016                  //  2097152  u32 pos per point id
#define WS_SOM      71303168                  //  4194304  float2 om per pos
#define WS_TOTAL    75497472

__device__ inline int point_bin(float om0, float om1)
{
    const float TWO_PI = 6.2831853071795864769f;
    const float tm0 = (om0 * 512.0f) / TWO_PI;
    const float tm1 = (om1 * 512.0f) / TWO_PI;
    const int cx = ((int)floorf(tm0)) & 511;
    const int cy = ((int)floorf(tm1)) & 511;
    return ((cx >> 4) << 5) | (cy >> 4);      // [0, 1024)
}

// quad broadcast: every lane receives lane (quadbase+O)'s value. VALU op,
// stays off the LDS pipe. Only called from fully-active quads.
template<int O>
__device__ inline half2_t qbc(half2_t v)
{
    int i;
    __builtin_memcpy(&i, &v, 4);
    i = __builtin_amdgcn_mov_dpp(i, (O | (O << 2) | (O << 4) | (O << 6)),
                                 0xf, 0xf, true);
    half2_t r;
    __builtin_memcpy(&r, &i, 4);
    return r;
}

// ---------------------------------------------------------------------------
// Fused transpose+hist. Blocks [0, TBLKS): transpose 256 consecutive cells
// via LDS. Blocks [TBLKS, TBLKS+NBLK): per-block LDS histogram ->
// blockHist[bin][blk] (bin-major). Pass blockHist=nullptr (grid=TBLKS) to
// run transpose only (middle path).
// ---------------------------------------------------------------------------
__global__ __launch_bounds__(256) void transpose_hist(
    const float* __restrict__ x, float4* __restrict__ xt,
    const float* __restrict__ om, unsigned* __restrict__ blockHist)
{
    __shared__ float s[32][260];   // 33280 B; hist aliases first 8192 B
    const int t = threadIdx.x;

    if (blockHist != nullptr && blockIdx.x >= TBLKS) {
        // ---- histogram body (256 threads, 8 iters) ----------------------
        unsigned* h = (unsigned*)s;               // [NBINS]
        const int blk = blockIdx.x - TBLKS;
#pragma unroll
        for (int i = 0; i < NBINS / 256; ++i) h[t + i * 256] = 0u;
        __syncthreads();
#pragma unroll
        for (int i = 0; i < PPB / 256; ++i) {
            const int id = blk * PPB + i * 256 + t;
            const int b = id >> 18, m = id & (KLEN - 1);
            const float om0 = om[(size_t)(b * 2 + 0) * KLEN + m];
            const float om1 = om[(size_t)(b * 2 + 1) * KLEN + m];
            const int g = (b << 10) | point_bin(om0, om1);
            atomicAdd(&h[g], 1u);
        }
        __syncthreads();
#pragma unroll
        for (int i = 0; i < NBINS / 256; ++i) {
            const int bin = t + i * 256;
            blockHist[(size_t)bin * NBLK + blk] = h[bin];   // strided once
        }
        return;
    }

    // ---- transpose body -------------------------------------------------
    const int blk   = blockIdx.x;            // [0, TBLKS)
    const int base  = blk * 256;
    const int b     = base >> 18;
    const int cell0 = base & (PLANE - 1);

    const float* xb = x + (size_t)b * 32 * PLANE + cell0;
#pragma unroll
    for (int i = 0; i < 8; ++i) {
        const int fidx = i * 256 + t;        // [0, 2048)
        const int pl = fidx >> 6;            // wave-uniform plane
        const int j  = fidx & 63;
        const float4 v = *(const float4*)(xb + (size_t)pl * PLANE + j * 4);
        *(float4*)&s[pl][j * 4] = v;
    }
    __syncthreads();
#pragma unroll
    for (int i = 0; i < 4; ++i) {
        const int chunk = i * 256 + t;       // [0, 1024)
        const int cell = chunk >> 2, q = chunk & 3;
        H8 rec;
#pragma unroll
        for (int cc = 0; cc < 4; ++cc) {
            const int c = q * 4 + cc;
            rec.h[cc] = half2_t{(_Float16)s[2 * c][cell],
                                (_Float16)s[2 * c + 1][cell]};
        }
        xt[((size_t)b * PLANE + cell0 + cell) * 4 + q] = *(const float4*)&rec;
    }
}

// ---------------------------------------------------------------------------
// Sort pass 2: wave-per-bin exclusive scan over the NBLK block counts.
// 16 waves/block, one bin per wave, zero barriers: lane holds 4 consecutive
// counts, wave-scan via __shfl_up. Grid = NBINS/16.
// ---------------------------------------------------------------------------
__global__ __launch_bounds__(1024) void scan_bins(
    unsigned* __restrict__ blockHist, unsigned* __restrict__ binTotal)
{
    const int t    = threadIdx.x;
    const int lane = t & 63;
    const int wave = t >> 6;
    const int bin  = blockIdx.x * 16 + wave;

    uint4 v = *(const uint4*)&blockHist[(size_t)bin * NBLK + lane * 4];
    const unsigned tot = v.x + v.y + v.z + v.w;

    unsigned s = tot;                          // inclusive wave scan of tot
#pragma unroll
    for (int d = 1; d < 64; d <<= 1) {
        const unsigned x = __shfl_up(s, d);
        if (lane >= d) s += x;
    }
    const unsigned excl = s - tot;             // exclusive prefix for lane

    uint4 o;
    o.x = excl;
    o.y = excl + v.x;
    o.z = excl + v.x + v.y;
    o.w = excl + v.x + v.y + v.z;
    *(uint4*)&blockHist[(size_t)bin * NBLK + lane * 4] = o;
    if (lane == 63) binTotal[bin] = s;         // bin total
}

// ---------------------------------------------------------------------------
// Sort pass 3: final positions. Wave-based scan of btot gives bin bases
// (block 0 publishes them to global bbase for interp); LDS atomics give
// local rank within (block, bin). 1024 threads.
// ---------------------------------------------------------------------------
__global__ __launch_bounds__(1024) void scatter2(
    const float*    __restrict__ om,
    const unsigned* __restrict__ blockHist,
    const unsigned* __restrict__ btot,
    unsigned* __restrict__ bbase,
    unsigned* __restrict__ inv,
    float2* __restrict__ som)
{
    __shared__ unsigned h[NBINS];
    __shared__ unsigned bbs[NBINS];
    __shared__ unsigned wsum[16];
    const int t = threadIdx.x, blk = blockIdx.x;
    const int lane = t & 63, wave = t >> 6;

    // exclusive scan of btot -> bbs: wave scan + 1-barrier cross-wave fixup
    const unsigned v0 = btot[t * 2], v1 = btot[t * 2 + 1];
    const unsigned tot = v0 + v1;
    unsigned s = tot;
#pragma unroll
    for (int d = 1; d < 64; d <<= 1) {
        const unsigned x = __shfl_up(s, d);
        if (lane >= d) s += x;
    }
    if (lane == 63) wsum[wave] = s;
#pragma unroll
    for (int i = 0; i < NBINS / 1024; ++i) h[t + i * 1024] = 0u;
    __syncthreads();
    unsigned wp = 0;
#pragma unroll
    for (int i = 0; i < 16; ++i) wp += (i < wave) ? wsum[i] : 0u;
    const unsigned excl = wp + s - tot;
    bbs[t * 2]     = excl;
    bbs[t * 2 + 1] = excl + v0;
    if (blk == 0) {                           // publish for interp_bins
        bbase[t * 2]     = excl;
        bbase[t * 2 + 1] = excl + v0;
    }
    __syncthreads();

#pragma unroll
    for (int i = 0; i < PPB / 1024; ++i) {
        const int id = blk * PPB + i * 1024 + t;
        const int b = id >> 18, m = id & (KLEN - 1);
        const float om0 = om[(size_t)(b * 2 + 0) * KLEN + m];
        const float om1 = om[(size_t)(b * 2 + 1) * KLEN + m];
        const int g = (b << 10) | point_bin(om0, om1);
        const unsigned r = atomicAdd(&h[g], 1u);
        const unsigned pos = bbs[g] + blockHist[(size_t)g * NBLK + blk] + r;
        inv[id]  = pos;
        som[pos] = make_float2(om0, om1);
    }
}

// ---------------------------------------------------------------------------
// Main interp: ONE BLOCK PER BIN, 512 threads (8 waves -> 32 waves/CU at 4
// resident blocks; was 16 with 256-thread blocks). Stage the bin's 21x21
// halo tile into LDS (proven TQ=5 record-pad layout), then all gathers are
// ds_read_b128. 4 lanes/point; coefficient pairs DPP-quad-shared. Bin range
// from precomputed bbase (2 loads).
// ---------------------------------------------------------------------------
__global__ __launch_bounds__(512) void interp_bins(
    const float2*   __restrict__ som,
    const float*    __restrict__ t0,
    const float*    __restrict__ t1,
    const float4*   __restrict__ xt,
    const unsigned* __restrict__ bbase,
    float4*         __restrict__ osort)
{
    __shared__ float4 tile[TROWS * TROWS * TQ];   // 2205 f4 = 35280 B
    const int bin = blockIdx.x;
    const int t   = threadIdx.x;
    const int b   = bin >> 10;
    const int cx0 = ((bin >> 5) & 31) << 4;
    const int cy0 = (bin & 31) << 4;

    const unsigned p0  = bbase[bin];
    const unsigned p1e = (bin == NBINS - 1) ? (unsigned)NPTS : bbase[bin + 1];
    const int cnt = (int)(p1e - p0);

    // ---- stage halo tile: 441 records x 4 chunks, coalesced rows --------
    const float4* rec = xt + ((size_t)b << 20);   // b * PLANE * 4 chunks
    for (int f = t; f < TROWS * TROWS * 4; f += 512) {
        const int r = f >> 2, q = f & 3;
        const int row = r / TROWS;                // const-div -> magic mul
        const int col = r - row * TROWS;
        const int gr = (cx0 - 2 + row) & 511;
        const int gc = (cy0 - 2 + col) & 511;
        tile[r * TQ + q] = rec[(((size_t)((gr << 9) | gc)) << 2) + q];
    }
    __syncthreads();

    const int lane = t & 3;
    for (int base = 0; base < cnt; base += 128) {
        const int idx = base + (t >> 2);
        if (idx >= cnt) continue;                 // whole quad skips together
        const int pos = (int)p0 + idx;

        const float2 o = som[pos];
        const float om0 = o.x, om1 = o.y;

        const float TWO_PI = 6.2831853071795864769f;
        const float tm0 = (om0 * 512.0f) / TWO_PI;
        const float tm1 = (om1 * 512.0f) / TWO_PI;

        const float koff0 = 1.0f + floorf(tm0 - 3.0f);
        const float koff1 = 1.0f + floorf(tm1 - 3.0f);
        const int   k0    = (int)koff0;
        const int   k1    = (int)koff1;

        // c0: all 6, every lane (outer factor). c1: only this lane's j1s.
        float c0r[6], c0i[6];
        int   loff[6];
#pragma unroll
        for (int j = 0; j < 6; ++j) {
            const float g0 = koff0 + (float)j;
            const int   d0 = (int)rintf((tm0 - g0) * 1024.0f) + TBL_CTR;
            c0r[j] = t0[d0];
            c0i[j] = t0[TBL_LEN + d0];
            loff[j] = ((k1 + j - cy0 + 2) & 511) * TQ;   // in [0, 20]*TQ
        }
        const int j1a = lane;                       // pair A owner: lane j1
        const int j1b = (lane < 2) ? lane + 4 : lane;   // pair B (lanes 0,1)
        const int d1a = (int)rintf((tm1 - (koff1 + (float)j1a)) * 1024.0f) + TBL_CTR;
        const int d1b = (int)rintf((tm1 - (koff1 + (float)j1b)) * 1024.0f) + TBL_CTR;
        const float c1ra = t1[d1a], c1ia = t1[TBL_LEN + d1a];
        const float c1rb = t1[d1b], c1ib = t1[TBL_LEN + d1b];

        float acr[4] = {0.f, 0.f, 0.f, 0.f};
        float aci[4] = {0.f, 0.f, 0.f, 0.f};

#define KB_DO_J1(JJ, OWNER, PP1, PP2)                                         \
        do {                                                                  \
            const half2_t p1 = qbc<OWNER>(PP1);                               \
            const half2_t p2 = qbc<OWNER>(PP2);                               \
            const float4 raw = rowp[loff[JJ]];                                \
            const H8 v = *(const H8*)&raw;                                    \
            _Pragma("unroll")                                                 \
            for (int cc = 0; cc < 4; ++cc) {                                  \
                acr[cc] = __builtin_amdgcn_fdot2(v.h[cc], p1, acr[cc], false);\
                aci[cc] = __builtin_amdgcn_fdot2(v.h[cc], p2, aci[cc], false);\
            }                                                                 \
        } while (0)

#pragma unroll
        for (int j0 = 0; j0 < 6; ++j0) {
            const int rIdx = (k0 + j0 - cx0 + 2) & 511;  // in [0, 20]
            const float4* rowp = &tile[rIdx * (TROWS * TQ) + lane];
            const float ar = c0r[j0], ai = c0i[j0];
            // this lane's pairs (same f32 math every lane ran pre-R11)
            const float crA = ar * c1ra - ai * c1ia;
            const float ciA = ar * c1ia + ai * c1ra;
            const float crB = ar * c1rb - ai * c1ib;
            const float ciB = ar * c1ib + ai * c1rb;
            const half2_t pA1 = {(_Float16)crA, (_Float16)(-ciA)};
            const half2_t pA2 = {(_Float16)ciA, (_Float16)crA};
            const half2_t pB1 = {(_Float16)crB, (_Float16)(-ciB)};
            const half2_t pB2 = {(_Float16)ciB, (_Float16)crB};

            KB_DO_J1(0, 0, pA1, pA2);
            KB_DO_J1(1, 1, pA1, pA2);
            KB_DO_J1(2, 2, pA1, pA2);
            KB_DO_J1(3, 3, pA1, pA2);
            KB_DO_J1(4, 0, pB1, pB2);
            KB_DO_J1(5, 1, pB1, pB2);
        }
#undef KB_DO_J1

        // phase twist: exp(i * (om0+om1)*128); |ph| <= 128 rev -> native ok
        const float ph = om0 * 128.0f + om1 * 128.0f;
        const float s = __sinf(ph), c = __cosf(ph);

        H8 outrec;
#pragma unroll
        for (int cc = 0; cc < 4; ++cc) {
            const float yr = acr[cc] * c - aci[cc] * s;
            const float yi = acr[cc] * s + aci[cc] * c;
            outrec.h[cc] = half2_t{(_Float16)yr, (_Float16)yi};
        }
        osort[(size_t)pos * 4 + lane] = *(const float4*)&outrec;   // coalesced
    }
}

// ---------------------------------------------------------------------------
// Unsort: thread per point id; gather 64 B record from osort, store coalesced
// into final (b,c,ri,m) layout.
// ---------------------------------------------------------------------------
__global__ __launch_bounds__(256) void unsort_kernel(
    const unsigned* __restrict__ inv,
    const float4*   __restrict__ osort,
    float*          __restrict__ out)
{
    const int id = blockIdx.x * blockDim.x + threadIdx.x;   // [0, NPTS)
    const int b = id >> 18, m = id & (KLEN - 1);
    const unsigned pos = inv[id];
    const float4* rp = osort + (size_t)pos * 4;

    float4 raw[4];
#pragma unroll
    for (int q = 0; q < 4; ++q) raw[q] = rp[q];

    float* ob = out + (size_t)b * NCOILS * 2 * KLEN + m;
#pragma unroll
    for (int q = 0; q < 4; ++q) {
        const H8 v = *(const H8*)&raw[q];
#pragma unroll
        for (int cc = 0; cc < 4; ++cc) {
            const int coil = q * 4 + cc;
            ob[(size_t)(2 * coil)     * KLEN] = (float)v.h[cc].x;
            ob[(size_t)(2 * coil + 1) * KLEN] = (float)v.h[cc].y;
        }
    }
}

// ---------------------------------------------------------------------------
// Middle path (ws >= xt only): direct-order interp (4 lanes/point).
// ---------------------------------------------------------------------------
__global__ __launch_bounds__(256) void interp_direct(
    const float*  __restrict__ om,
    const float*  __restrict__ t0,
    const float*  __restrict__ t1,
    const float4* __restrict__ xt,
    float*        __restrict__ out)
{
    const int tid  = blockIdx.x * blockDim.x + threadIdx.x;
    const int lane = tid & 3;
    const int p    = tid >> 2;
    const int b    = p >> 18;
    const int m    = p & (KLEN - 1);

    const float om0 = om[(size_t)(b * 2 + 0) * KLEN + m];
    const float om1 = om[(size_t)(b * 2 + 1) * KLEN + m];

    const float TWO_PI = 6.2831853071795864769f;
    const float tm0 = (om0 * 512.0f) / TWO_PI;
    const float tm1 = (om1 * 512.0f) / TWO_PI;
    const float koff0 = 1.0f + floorf(tm0 - 3.0f);
    const float koff1 = 1.0f + floorf(tm1 - 3.0f);
    const int k0 = (int)koff0, k1 = (int)koff1;

    float c0r[6], c0i[6], c1r[6], c1i[6];
    int coff[6];
#pragma unroll
    for (int j = 0; j < 6; ++j) {
        const float g0 = koff0 + (float)j;
        const int d0 = (int)rintf((tm0 - g0) * 1024.0f) + TBL_CTR;
        c0r[j] = t0[d0];
        c0i[j] = t0[TBL_LEN + d0];
        const float g1 = koff1 + (float)j;
        const int d1 = (int)rintf((tm1 - g1) * 1024.0f) + TBL_CTR;
        c1r[j] = t1[d1];
        c1i[j] = t1[TBL_LEN + d1];
        coff[j] = ((k1 + j) & 511) << 2;
    }

    const float4* rec = xt + ((size_t)b << 20);
    float acr[4] = {0.f, 0.f, 0.f, 0.f};
    float aci[4] = {0.f, 0.f, 0.f, 0.f};
#pragma unroll
    for (int j0 = 0; j0 < 6; ++j0) {
        const int roff = (k0 + j0) & 511;
        const float4* rowp = rec + ((size_t)roff << 11) + lane;
        const float ar = c0r[j0], ai = c0i[j0];
#pragma unroll
        for (int j1 = 0; j1 < 6; ++j1) {
            const float br = c1r[j1], bi = c1i[j1];
            const float cr = ar * br - ai * bi;
            const float ci = ar * bi + ai * br;
            const half2_t p1 = {(_Float16)cr, (_Float16)(-ci)};
            const half2_t p2 = {(_Float16)ci, (_Float16)cr};
            const float4 raw = rowp[coff[j1]];
            const H8 v = *(const H8*)&raw;
#pragma unroll
            for (int cc = 0; cc < 4; ++cc) {
                acr[cc] = __builtin_amdgcn_fdot2(v.h[cc], p1, acr[cc], false);
                aci[cc] = __builtin_amdgcn_fdot2(v.h[cc], p2, aci[cc], false);
            }
        }
    }

    const float ph = om0 * 128.0f + om1 * 128.0f;
    const float s = sinf(ph), c = cosf(ph);
#pragma unroll
    for (int cc = 0; cc < 4; ++cc) {
        const float yr = acr[cc] * c - aci[cc] * s;
        const float yi = acr[cc] * s + aci[cc] * c;
        const int coil = lane * 4 + cc;
        const size_t ob = ((size_t)(b * NCOILS + coil) * 2) * KLEN + m;
        out[ob]        = yr;
        out[ob + KLEN] = yi;
    }
}

// ---------------------------------------------------------------------------
// Fallback (tiny ws): one thread per point, original layout.
// ---------------------------------------------------------------------------
__global__ __launch_bounds__(256) void interp_fallback(
    const float* __restrict__ om,
    const float* __restrict__ t0,
    const float* __restrict__ t1,
    const float* __restrict__ x,
    float*       __restrict__ out)
{
    const int p = blockIdx.x * blockDim.x + threadIdx.x;
    const int b = p >> 18;
    const int m = p & (KLEN - 1);

    const float om0 = om[(size_t)(b * 2 + 0) * KLEN + m];
    const float om1 = om[(size_t)(b * 2 + 1) * KLEN + m];
    const float TWO_PI = 6.2831853071795864769f;
    const float tm0 = (om0 * 512.0f) / TWO_PI;
    const float tm1 = (om1 * 512.0f) / TWO_PI;
    const float koff0 = 1.0f + floorf(tm0 - 3.0f);
    const float koff1 = 1.0f + floorf(tm1 - 3.0f);
    const int k0 = (int)koff0, k1 = (int)koff1;

    float c0r[6], c0i[6], c1r[6], c1i[6];
    int roff[6], coff[6];
#pragma unroll
    for (int j = 0; j < 6; ++j) {
        const float g0 = koff0 + (float)j;
        const int d0 = (int)rintf((tm0 - g0) * 1024.0f) + TBL_CTR;
        c0r[j] = t0[d0];
        c0i[j] = t0[TBL_LEN + d0];
        const float g1 = koff1 + (float)j;
        const int d1 = (int)rintf((tm1 - g1) * 1024.0f) + TBL_CTR;
        c1r[j] = t1[d1];
        c1i[j] = t1[TBL_LEN + d1];
        roff[j] = (k0 + j) & 511;
        coff[j] = (k1 + j) & 511;
    }

    float accr[NCOILS], acci[NCOILS];
#pragma unroll
    for (int c = 0; c < NCOILS; ++c) { accr[c] = 0.f; acci[c] = 0.f; }

    const float* xb = x + (size_t)b * NCOILS * 2 * PLANE;
#pragma unroll
    for (int j0 = 0; j0 < 6; ++j0) {
        const float ar = c0r[j0], ai = c0i[j0];
        const int rb = roff[j0] * GY;
#pragma unroll
        for (int j1 = 0; j1 < 6; ++j1) {
            const float br = c1r[j1], bi = c1i[j1];
            const float cr = ar * br - ai * bi;
            const float ci = ar * bi + ai * br;
            const int ai_idx = rb + coff[j1];
#pragma unroll
            for (int c = 0; c < NCOILS; ++c) {
                const float dr = xb[(size_t)c * (2 * PLANE) + ai_idx];
                const float di = xb[(size_t)c * (2 * PLANE) + PLANE + ai_idx];
                accr[c] += cr * dr - ci * di;
                acci[c] += cr * di + ci * dr;
            }
        }
    }

    const float ph = om0 * 128.0f + om1 * 128.0f;
    const float s = sinf(ph), c = cosf(ph);
#pragma unroll
    for (int cc = 0; cc < NCOILS; ++cc) {
        const float yr = accr[cc] * c - acci[cc] * s;
        const float yi = accr[cc] * s + acci[cc] * c;
        size_t ob = ((size_t)(b * NCOILS + cc) * 2) * KLEN + m;
        out[ob]        = yr;
        out[ob + KLEN] = yi;
    }
}

extern "C" void kernel_launch(void* const* d_in, const int* in_sizes, int n_in,
                              void* d_out, int out_size, void* d_ws, size_t ws_size,
                              hipStream_t stream)
{
    const float* x  = (const float*)d_in[0];
    const float* om = (const float*)d_in[1];
    const float* t0 = (const float*)d_in[2];
    const float* t1 = (const float*)d_in[3];
    float* out = (float*)d_out;

    char* ws = (char*)d_ws;
    const size_t xt_bytes = (size_t)NBATCH * PLANE * NCOILS * 2 * sizeof(__half);

    if (ws_size >= (size_t)WS_TOTAL) {
        float4*   xt     = (float4*)(ws + WS_XT);
        float4*   osort  = (float4*)(ws + WS_OSORT);
        unsigned* bhist  = (unsigned*)(ws + WS_BHIST);
        unsigned* btot   = (unsigned*)(ws + WS_BTOT);
        unsigned* bbase  = (unsigned*)(ws + WS_BBASE);
        unsigned* inv    = (unsigned*)(ws + WS_INV);
        float2*   som    = (float2*)(ws + WS_SOM);

        transpose_hist<<<TBLKS + NBLK, 256, 0, stream>>>(x, xt, om, bhist);
        scan_bins<<<NBINS / 16, 1024, 0, stream>>>(bhist, btot);
        scatter2<<<NBLK, 1024, 0, stream>>>(om, bhist, btot, bbase, inv, som);
        interp_bins<<<NBINS, 512, 0, stream>>>(som, t0, t1, xt, bbase, osort);
        unsort_kernel<<<NPTS / 256, 256, 0, stream>>>(inv, osort, out);
    } else if (ws_size >= xt_bytes) {
        float4* xt = (float4*)ws;
        transpose_hist<<<TBLKS, 256, 0, stream>>>(x, xt, om, nullptr);
        interp_direct<<<NPTS * 4 / 256, 256, 0, stream>>>(om, t0, t1, xt, out);
    } else {
        interp_fallback<<<NPTS / 256, 256, 0, stream>>>(om, t0, t1, x, out);
    }
}

// Round 9
// 203.578 us; speedup vs baseline: 1.0906x; 1.0437x over previous
//
#include <hip/hip_runtime.h>
#include <hip/hip_fp16.h>

// KbInterpForw: table-based KB NUFFT interpolation, forward.
// x: (2,16,2,512,512) f32, om: (2,2,262144) f32, tables: (2,6145) f32 each.
// out: (2,16,2,262144) f32.
//
// R15 (on R14's 212.5 us):
//  - interp_bins is at its VALU-issue floor (VALU-busy 91k cyc/CU ~= the
//    instruction-count estimate). Cut instructions: 2 lanes/point x 8 coils
//    (was 4 x 4). Setup/sincos/rotate now 2x redundant instead of 4x ->
//    ~23% fewer inst-lanes/point. R8's version of this failed at VGPR=200
//    pre-LDS-tile/pre-DPP; current baseline is VGPR=28, est. ~55 now.
//  - Pair ownership by lane parity: even lane owns j1={0,1,2}, odd {3,4,5};
//    DPP quad_perm [0,0,2,2]/[1,1,3,3] broadcasts within the 2-lane pair
//    only (pairs skip tails together -> DPP sources always active).
//  - Each lane reads its 2 chunks per record (2x ds_read_b128); total LDS
//    traffic unchanged. fdot2 order per coil unchanged -> same numerics.
//  - Sort pipeline (R14: fused transpose+hist, wave scans, 1024-thr
//    scatter) untouched.

#define KLEN      262144      // 2^18
#define GX        512
#define GY        512
#define NCOILS    16
#define NBATCH    2
#define TBL_LEN   6145        // 6*1024+1
#define TBL_CTR   3072
#define PLANE     (GX*GY)
#define NPTS      (NBATCH*KLEN)
#define NBINS     2048        // NBATCH * 32*32 tiles
#define NBLK      256         // sort blocks
#define PPB       2048        // points per sort block (NPTS/NBLK)
#define TBLKS     (NBATCH*PLANE/256)   // 8192 transpose blocks

#define TROWS     21          // 16 + 5 halo
#define TQ        5           // float4 slots per record in LDS (4 used + 1 pad)

typedef _Float16 half2_t __attribute__((ext_vector_type(2)));
struct alignas(16) H8 { half2_t h[4]; };   // 4 coils' (re,im) fp16 = 16 B

// ---------------------------------------------------------------------------
// ws layout (bytes). blockHist aliases osort (dead before interp writes
// osort). btot/bbase live in the unaliased gap after osort.
// ---------------------------------------------------------------------------
#define WS_XT       0                         // 33554432  fp16 grid records
#define WS_OSORT    33554432                  // 33554432  fp16 sorted outputs
#define WS_BHIST    33554432                  //  2097152  u32 [NBINS][NBLK] (alias osort)
#define WS_BTOT     67108864                  //     8192  u32 [NBINS]  NOT aliased
#define WS_BBASE    (67108864+8192)           //     8192  u32 [NBINS]  NOT aliased
#define WS_INV      69206016                  //  2097152  u32 pos per point id
#define WS_SOM      71303168                  //  4194304  float2 om per pos
#define WS_TOTAL    75497472

__device__ inline int point_bin(float om0, float om1)
{
    const float TWO_PI = 6.2831853071795864769f;
    const float tm0 = (om0 * 512.0f) / TWO_PI;
    const float tm1 = (om1 * 512.0f) / TWO_PI;
    const int cx = ((int)floorf(tm0)) & 511;
    const int cy = ((int)floorf(tm1)) & 511;
    return ((cx >> 4) << 5) | (cy >> 4);      // [0, 1024)
}

// quad-perm broadcast with explicit control byte. VALU op. Sources must be
// active lanes (we only reference lanes of the reader's own 2-lane pair).
template<int CTRL>
__device__ inline half2_t qbcc(half2_t v)
{
    int i;
    __builtin_memcpy(&i, &v, 4);
    i = __builtin_amdgcn_mov_dpp(i, CTRL, 0xf, 0xf, true);
    half2_t r;
    __builtin_memcpy(&r, &i, 4);
    return r;
}
#define DPP_EVEN 0xA0   // [0,0,2,2]: read even lane of own pair
#define DPP_ODD  0xF5   // [1,1,3,3]: read odd lane of own pair

// ---------------------------------------------------------------------------
// Fused transpose+hist. Blocks [0, TBLKS): transpose 256 consecutive cells
// via LDS. Blocks [TBLKS, TBLKS+NBLK): per-block LDS histogram ->
// blockHist[bin][blk] (bin-major). Pass blockHist=nullptr (grid=TBLKS) to
// run transpose only (middle path).
// ---------------------------------------------------------------------------
__global__ __launch_bounds__(256) void transpose_hist(
    const float* __restrict__ x, float4* __restrict__ xt,
    const float* __restrict__ om, unsigned* __restrict__ blockHist)
{
    __shared__ float s[32][260];   // 33280 B; hist aliases first 8192 B
    const int t = threadIdx.x;

    if (blockHist != nullptr && blockIdx.x >= TBLKS) {
        // ---- histogram body (256 threads, 8 iters) ----------------------
        unsigned* h = (unsigned*)s;               // [NBINS]
        const int blk = blockIdx.x - TBLKS;
#pragma unroll
        for (int i = 0; i < NBINS / 256; ++i) h[t + i * 256] = 0u;
        __syncthreads();
#pragma unroll
        for (int i = 0; i < PPB / 256; ++i) {
            const int id = blk * PPB + i * 256 + t;
            const int b = id >> 18, m = id & (KLEN - 1);
            const float om0 = om[(size_t)(b * 2 + 0) * KLEN + m];
            const float om1 = om[(size_t)(b * 2 + 1) * KLEN + m];
            const int g = (b << 10) | point_bin(om0, om1);
            atomicAdd(&h[g], 1u);
        }
        __syncthreads();
#pragma unroll
        for (int i = 0; i < NBINS / 256; ++i) {
            const int bin = t + i * 256;
            blockHist[(size_t)bin * NBLK + blk] = h[bin];   // strided once
        }
        return;
    }

    // ---- transpose body -------------------------------------------------
    const int blk   = blockIdx.x;            // [0, TBLKS)
    const int base  = blk * 256;
    const int b     = base >> 18;
    const int cell0 = base & (PLANE - 1);

    const float* xb = x + (size_t)b * 32 * PLANE + cell0;
#pragma unroll
    for (int i = 0; i < 8; ++i) {
        const int fidx = i * 256 + t;        // [0, 2048)
        const int pl = fidx >> 6;            // wave-uniform plane
        const int j  = fidx & 63;
        const float4 v = *(const float4*)(xb + (size_t)pl * PLANE + j * 4);
        *(float4*)&s[pl][j * 4] = v;
    }
    __syncthreads();
#pragma unroll
    for (int i = 0; i < 4; ++i) {
        const int chunk = i * 256 + t;       // [0, 1024)
        const int cell = chunk >> 2, q = chunk & 3;
        H8 rec;
#pragma unroll
        for (int cc = 0; cc < 4; ++cc) {
            const int c = q * 4 + cc;
            rec.h[cc] = half2_t{(_Float16)s[2 * c][cell],
                                (_Float16)s[2 * c + 1][cell]};
        }
        xt[((size_t)b * PLANE + cell0 + cell) * 4 + q] = *(const float4*)&rec;
    }
}

// ---------------------------------------------------------------------------
// Sort pass 2: wave-per-bin exclusive scan over the NBLK block counts.
// 16 waves/block, one bin per wave, zero barriers.
// ---------------------------------------------------------------------------
__global__ __launch_bounds__(1024) void scan_bins(
    unsigned* __restrict__ blockHist, unsigned* __restrict__ binTotal)
{
    const int t    = threadIdx.x;
    const int lane = t & 63;
    const int wave = t >> 6;
    const int bin  = blockIdx.x * 16 + wave;

    uint4 v = *(const uint4*)&blockHist[(size_t)bin * NBLK + lane * 4];
    const unsigned tot = v.x + v.y + v.z + v.w;

    unsigned s = tot;                          // inclusive wave scan of tot
#pragma unroll
    for (int d = 1; d < 64; d <<= 1) {
        const unsigned x = __shfl_up(s, d);
        if (lane >= d) s += x;
    }
    const unsigned excl = s - tot;             // exclusive prefix for lane

    uint4 o;
    o.x = excl;
    o.y = excl + v.x;
    o.z = excl + v.x + v.y;
    o.w = excl + v.x + v.y + v.z;
    *(uint4*)&blockHist[(size_t)bin * NBLK + lane * 4] = o;
    if (lane == 63) binTotal[bin] = s;         // bin total
}

// ---------------------------------------------------------------------------
// Sort pass 3: final positions. Wave-based scan of btot gives bin bases
// (block 0 publishes them to global bbase for interp); LDS atomics give
// local rank within (block, bin). 1024 threads.
// ---------------------------------------------------------------------------
__global__ __launch_bounds__(1024) void scatter2(
    const float*    __restrict__ om,
    const unsigned* __restrict__ blockHist,
    const unsigned* __restrict__ btot,
    unsigned* __restrict__ bbase,
    unsigned* __restrict__ inv,
    float2* __restrict__ som)
{
    __shared__ unsigned h[NBINS];
    __shared__ unsigned bbs[NBINS];
    __shared__ unsigned wsum[16];
    const int t = threadIdx.x, blk = blockIdx.x;
    const int lane = t & 63, wave = t >> 6;

    // exclusive scan of btot -> bbs: wave scan + 1-barrier cross-wave fixup
    const unsigned v0 = btot[t * 2], v1 = btot[t * 2 + 1];
    const unsigned tot = v0 + v1;
    unsigned s = tot;
#pragma unroll
    for (int d = 1; d < 64; d <<= 1) {
        const unsigned x = __shfl_up(s, d);
        if (lane >= d) s += x;
    }
    if (lane == 63) wsum[wave] = s;
#pragma unroll
    for (int i = 0; i < NBINS / 1024; ++i) h[t + i * 1024] = 0u;
    __syncthreads();
    unsigned wp = 0;
#pragma unroll
    for (int i = 0; i < 16; ++i) wp += (i < wave) ? wsum[i] : 0u;
    const unsigned excl = wp + s - tot;
    bbs[t * 2]     = excl;
    bbs[t * 2 + 1] = excl + v0;
    if (blk == 0) {                           // publish for interp_bins
        bbase[t * 2]     = excl;
        bbase[t * 2 + 1] = excl + v0;
    }
    __syncthreads();

#pragma unroll
    for (int i = 0; i < PPB / 1024; ++i) {
        const int id = blk * PPB + i * 1024 + t;
        const int b = id >> 18, m = id & (KLEN - 1);
        const float om0 = om[(size_t)(b * 2 + 0) * KLEN + m];
        const float om1 = om[(size_t)(b * 2 + 1) * KLEN + m];
        const int g = (b << 10) | point_bin(om0, om1);
        const unsigned r = atomicAdd(&h[g], 1u);
        const unsigned pos = bbs[g] + blockHist[(size_t)g * NBLK + blk] + r;
        inv[id]  = pos;
        som[pos] = make_float2(om0, om1);
    }
}

// ---------------------------------------------------------------------------
// Main interp: ONE BLOCK PER BIN, 512 threads. Stage the bin's 21x21 halo
// tile into LDS (proven TQ=5 record-pad layout). 2 LANES PER POINT, 8 coils
// each (even lane: chunks 0,1 / coils 0-7; odd: chunks 2,3 / coils 8-15).
// Coefficient pairs owned by lane parity (even: j1 0-2, odd: j1 3-5),
// shared via 2-lane DPP quad_perm. Bin range from precomputed bbase.
// ---------------------------------------------------------------------------
__global__ __launch_bounds__(512) void interp_bins(
    const float2*   __restrict__ som,
    const float*    __restrict__ t0,
    const float*    __restrict__ t1,
    const float4*   __restrict__ xt,
    const unsigned* __restrict__ bbase,
    float4*         __restrict__ osort)
{
    __shared__ float4 tile[TROWS * TROWS * TQ];   // 2205 f4 = 35280 B
    const int bin = blockIdx.x;
    const int t   = threadIdx.x;
    const int b   = bin >> 10;
    const int cx0 = ((bin >> 5) & 31) << 4;
    const int cy0 = (bin & 31) << 4;

    const unsigned p0  = bbase[bin];
    const unsigned p1e = (bin == NBINS - 1) ? (unsigned)NPTS : bbase[bin + 1];
    const int cnt = (int)(p1e - p0);

    // ---- stage halo tile: 441 records x 4 chunks, coalesced rows --------
    const float4* rec = xt + ((size_t)b << 20);   // b * PLANE * 4 chunks
    for (int f = t; f < TROWS * TROWS * 4; f += 512) {
        const int r = f >> 2, q = f & 3;
        const int row = r / TROWS;                // const-div -> magic mul
        const int col = r - row * TROWS;
        const int gr = (cx0 - 2 + row) & 511;
        const int gc = (cy0 - 2 + col) & 511;
        tile[r * TQ + q] = rec[(((size_t)((gr << 9) | gc)) << 2) + q];
    }
    __syncthreads();

    const int lane = t & 1;                    // pair lane
    for (int base = 0; base < cnt; base += 256) {
        const int idx = base + (t >> 1);
        if (idx >= cnt) continue;              // lane-pairs skip together
        const int pos = (int)p0 + idx;

        const float2 o = som[pos];
        const float om0 = o.x, om1 = o.y;

        const float TWO_PI = 6.2831853071795864769f;
        const float tm0 = (om0 * 512.0f) / TWO_PI;
        const float tm1 = (om1 * 512.0f) / TWO_PI;

        const float koff0 = 1.0f + floorf(tm0 - 3.0f);
        const float koff1 = 1.0f + floorf(tm1 - 3.0f);
        const int   k0    = (int)koff0;
        const int   k1    = (int)koff1;

        // c0: all 6, every lane (outer factor). c1: this lane's 3 j1s.
        float c0r[6], c0i[6];
        int   loff[6];
#pragma unroll
        for (int j = 0; j < 6; ++j) {
            const float g0 = koff0 + (float)j;
            const int   d0 = (int)rintf((tm0 - g0) * 1024.0f) + TBL_CTR;
            c0r[j] = t0[d0];
            c0i[j] = t0[TBL_LEN + d0];
            loff[j] = ((k1 + j - cy0 + 2) & 511) * TQ;   // in [0, 20]*TQ
        }
        const int j1o = 3 * lane;              // own j1 base: 0 or 3
        float c1r[3], c1i[3];
#pragma unroll
        for (int k = 0; k < 3; ++k) {
            const int d1 = (int)rintf((tm1 - (koff1 + (float)(j1o + k))) * 1024.0f)
                           + TBL_CTR;
            c1r[k] = t1[d1];
            c1i[k] = t1[TBL_LEN + d1];
        }

        float acr[8], aci[8];
#pragma unroll
        for (int c = 0; c < 8; ++c) { acr[c] = 0.f; aci[c] = 0.f; }

#define KB_DO_J1(JJ, CTRL, PP1, PP2)                                          \
        do {                                                                  \
            const half2_t p1 = qbcc<CTRL>(PP1);                               \
            const half2_t p2 = qbcc<CTRL>(PP2);                               \
            const float4 raw0 = rowp[loff[JJ]];                               \
            const float4 raw1 = rowp[loff[JJ] + 1];                           \
            const H8 v0 = *(const H8*)&raw0;                                  \
            const H8 v1 = *(const H8*)&raw1;                                  \
            _Pragma("unroll")                                                 \
            for (int cc = 0; cc < 4; ++cc) {                                  \
                acr[cc]   = __builtin_amdgcn_fdot2(v0.h[cc], p1, acr[cc],   false);\
                aci[cc]   = __builtin_amdgcn_fdot2(v0.h[cc], p2, aci[cc],   false);\
                acr[4+cc] = __builtin_amdgcn_fdot2(v1.h[cc], p1, acr[4+cc], false);\
                aci[4+cc] = __builtin_amdgcn_fdot2(v1.h[cc], p2, aci[4+cc], false);\
            }                                                                 \
        } while (0)

#pragma unroll
        for (int j0 = 0; j0 < 6; ++j0) {
            const int rIdx = (k0 + j0 - cx0 + 2) & 511;  // in [0, 20]
            const float4* rowp = &tile[rIdx * (TROWS * TQ) + 2 * lane];
            const float ar = c0r[j0], ai = c0i[j0];
            // this lane's 3 pairs (same f32 expressions as pre-R15)
            const float crA = ar * c1r[0] - ai * c1i[0];
            const float ciA = ar * c1i[0] + ai * c1r[0];
            const float crB = ar * c1r[1] - ai * c1i[1];
            const float ciB = ar * c1i[1] + ai * c1r[1];
            const float crC = ar * c1r[2] - ai * c1i[2];
            const float ciC = ar * c1i[2] + ai * c1r[2];
            const half2_t pA1 = {(_Float16)crA, (_Float16)(-ciA)};
            const half2_t pA2 = {(_Float16)ciA, (_Float16)crA};
            const half2_t pB1 = {(_Float16)crB, (_Float16)(-ciB)};
            const half2_t pB2 = {(_Float16)ciB, (_Float16)crB};
            const half2_t pC1 = {(_Float16)crC, (_Float16)(-ciC)};
            const half2_t pC2 = {(_Float16)ciC, (_Float16)crC};

            KB_DO_J1(0, DPP_EVEN, pA1, pA2);
            KB_DO_J1(1, DPP_EVEN, pB1, pB2);
            KB_DO_J1(2, DPP_EVEN, pC1, pC2);
            KB_DO_J1(3, DPP_ODD,  pA1, pA2);
            KB_DO_J1(4, DPP_ODD,  pB1, pB2);
            KB_DO_J1(5, DPP_ODD,  pC1, pC2);
        }
#undef KB_DO_J1

        // phase twist: exp(i * (om0+om1)*128); |ph| <= 128 rev -> native ok
        const float ph = om0 * 128.0f + om1 * 128.0f;
        const float s = __sinf(ph), c = __cosf(ph);

        float4* op = osort + (size_t)pos * 4 + 2 * lane;
#pragma unroll
        for (int q = 0; q < 2; ++q) {
            H8 outrec;
#pragma unroll
            for (int cc = 0; cc < 4; ++cc) {
                const int a = q * 4 + cc;
                const float yr = acr[a] * c - aci[a] * s;
                const float yi = acr[a] * s + aci[a] * c;
                outrec.h[cc] = half2_t{(_Float16)yr, (_Float16)yi};
            }
            op[q] = *(const float4*)&outrec;   // pairs cover 64 B coalesced
        }
    }
}

// ---------------------------------------------------------------------------
// Unsort: thread per point id; gather 64 B record from osort, store coalesced
// into final (b,c,ri,m) layout.
// ---------------------------------------------------------------------------
__global__ __launch_bounds__(256) void unsort_kernel(
    const unsigned* __restrict__ inv,
    const float4*   __restrict__ osort,
    float*          __restrict__ out)
{
    const int id = blockIdx.x * blockDim.x + threadIdx.x;   // [0, NPTS)
    const int b = id >> 18, m = id & (KLEN - 1);
    const unsigned pos = inv[id];
    const float4* rp = osort + (size_t)pos * 4;

    float4 raw[4];
#pragma unroll
    for (int q = 0; q < 4; ++q) raw[q] = rp[q];

    float* ob = out + (size_t)b * NCOILS * 2 * KLEN + m;
#pragma unroll
    for (int q = 0; q < 4; ++q) {
        const H8 v = *(const H8*)&raw[q];
#pragma unroll
        for (int cc = 0; cc < 4; ++cc) {
            const int coil = q * 4 + cc;
            ob[(size_t)(2 * coil)     * KLEN] = (float)v.h[cc].x;
            ob[(size_t)(2 * coil + 1) * KLEN] = (float)v.h[cc].y;
        }
    }
}

// ---------------------------------------------------------------------------
// Middle path (ws >= xt only): direct-order interp (4 lanes/point).
// ---------------------------------------------------------------------------
__global__ __launch_bounds__(256) void interp_direct(
    const float*  __restrict__ om,
    const float*  __restrict__ t0,
    const float*  __restrict__ t1,
    const float4* __restrict__ xt,
    float*        __restrict__ out)
{
    const int tid  = blockIdx.x * blockDim.x + threadIdx.x;
    const int lane = tid & 3;
    const int p    = tid >> 2;
    const int b    = p >> 18;
    const int m    = p & (KLEN - 1);

    const float om0 = om[(size_t)(b * 2 + 0) * KLEN + m];
    const float om1 = om[(size_t)(b * 2 + 1) * KLEN + m];

    const float TWO_PI = 6.2831853071795864769f;
    const float tm0 = (om0 * 512.0f) / TWO_PI;
    const float tm1 = (om1 * 512.0f) / TWO_PI;
    const float koff0 = 1.0f + floorf(tm0 - 3.0f);
    const float koff1 = 1.0f + floorf(tm1 - 3.0f);
    const int k0 = (int)koff0, k1 = (int)koff1;

    float c0r[6], c0i[6], c1r[6], c1i[6];
    int coff[6];
#pragma unroll
    for (int j = 0; j < 6; ++j) {
        const float g0 = koff0 + (float)j;
        const int d0 = (int)rintf((tm0 - g0) * 1024.0f) + TBL_CTR;
        c0r[j] = t0[d0];
        c0i[j] = t0[TBL_LEN + d0];
        const float g1 = koff1 + (float)j;
        const int d1 = (int)rintf((tm1 - g1) * 1024.0f) + TBL_CTR;
        c1r[j] = t1[d1];
        c1i[j] = t1[TBL_LEN + d1];
        coff[j] = ((k1 + j) & 511) << 2;
    }

    const float4* rec = xt + ((size_t)b << 20);
    float acr[4] = {0.f, 0.f, 0.f, 0.f};
    float aci[4] = {0.f, 0.f, 0.f, 0.f};
#pragma unroll
    for (int j0 = 0; j0 < 6; ++j0) {
        const int roff = (k0 + j0) & 511;
        const float4* rowp = rec + ((size_t)roff << 11) + lane;
        const float ar = c0r[j0], ai = c0i[j0];
#pragma unroll
        for (int j1 = 0; j1 < 6; ++j1) {
            const float br = c1r[j1], bi = c1i[j1];
            const float cr = ar * br - ai * bi;
            const float ci = ar * bi + ai * br;
            const half2_t p1 = {(_Float16)cr, (_Float16)(-ci)};
            const half2_t p2 = {(_Float16)ci, (_Float16)cr};
            const float4 raw = rowp[coff[j1]];
            const H8 v = *(const H8*)&raw;
#pragma unroll
            for (int cc = 0; cc < 4; ++cc) {
                acr[cc] = __builtin_amdgcn_fdot2(v.h[cc], p1, acr[cc], false);
                aci[cc] = __builtin_amdgcn_fdot2(v.h[cc], p2, aci[cc], false);
            }
        }
    }

    const float ph = om0 * 128.0f + om1 * 128.0f;
    const float s = sinf(ph), c = cosf(ph);
#pragma unroll
    for (int cc = 0; cc < 4; ++cc) {
        const float yr = acr[cc] * c - aci[cc] * s;
        const float yi = acr[cc] * s + aci[cc] * c;
        const int coil = lane * 4 + cc;
        const size_t ob = ((size_t)(b * NCOILS + coil) * 2) * KLEN + m;
        out[ob]        = yr;
        out[ob + KLEN] = yi;
    }
}

// ---------------------------------------------------------------------------
// Fallback (tiny ws): one thread per point, original layout.
// ---------------------------------------------------------------------------
__global__ __launch_bounds__(256) void interp_fallback(
    const float* __restrict__ om,
    const float* __restrict__ t0,
    const float* __restrict__ t1,
    const float* __restrict__ x,
    float*       __restrict__ out)
{
    const int p = blockIdx.x * blockDim.x + threadIdx.x;
    const int b = p >> 18;
    const int m = p & (KLEN - 1);

    const float om0 = om[(size_t)(b * 2 + 0) * KLEN + m];
    const float om1 = om[(size_t)(b * 2 + 1) * KLEN + m];
    const float TWO_PI = 6.2831853071795864769f;
    const float tm0 = (om0 * 512.0f) / TWO_PI;
    const float tm1 = (om1 * 512.0f) / TWO_PI;
    const float koff0 = 1.0f + floorf(tm0 - 3.0f);
    const float koff1 = 1.0f + floorf(tm1 - 3.0f);
    const int k0 = (int)koff0, k1 = (int)koff1;

    float c0r[6], c0i[6], c1r[6], c1i[6];
    int roff[6], coff[6];
#pragma unroll
    for (int j = 0; j < 6; ++j) {
        const float g0 = koff0 + (float)j;
        const int d0 = (int)rintf((tm0 - g0) * 1024.0f) + TBL_CTR;
        c0r[j] = t0[d0];
        c0i[j] = t0[TBL_LEN + d0];
        const float g1 = koff1 + (float)j;
        const int d1 = (int)rintf((tm1 - g1) * 1024.0f) + TBL_CTR;
        c1r[j] = t1[d1];
        c1i[j] = t1[TBL_LEN + d1];
        roff[j] = (k0 + j) & 511;
        coff[j] = (k1 + j) & 511;
    }

    float accr[NCOILS], acci[NCOILS];
#pragma unroll
    for (int c = 0; c < NCOILS; ++c) { accr[c] = 0.f; acci[c] = 0.f; }

    const float* xb = x + (size_t)b * NCOILS * 2 * PLANE;
#pragma unroll
    for (int j0 = 0; j0 < 6; ++j0) {
        const float ar = c0r[j0], ai = c0i[j0];
        const int rb = roff[j0] * GY;
#pragma unroll
        for (int j1 = 0; j1 < 6; ++j1) {
            const float br = c1r[j1], bi = c1i[j1];
            const float cr = ar * br - ai * bi;
            const float ci = ar * bi + ai * br;
            const int ai_idx = rb + coff[j1];
#pragma unroll
            for (int c = 0; c < NCOILS; ++c) {
                const float dr = xb[(size_t)c * (2 * PLANE) + ai_idx];
                const float di = xb[(size_t)c * (2 * PLANE) + PLANE + ai_idx];
                accr[c] += cr * dr - ci * di;
                acci[c] += cr * di + ci * dr;
            }
        }
    }

    const float ph = om0 * 128.0f + om1 * 128.0f;
    const float s = sinf(ph), c = cosf(ph);
#pragma unroll
    for (int cc = 0; cc < NCOILS; ++cc) {
        const float yr = accr[cc] * c - acci[cc] * s;
        const float yi = accr[cc] * s + acci[cc] * c;
        size_t ob = ((size_t)(b * NCOILS + cc) * 2) * KLEN + m;
        out[ob]        = yr;
        out[ob + KLEN] = yi;
    }
}

extern "C" void kernel_launch(void* const* d_in, const int* in_sizes, int n_in,
                              void* d_out, int out_size, void* d_ws, size_t ws_size,
                              hipStream_t stream)
{
    const float* x  = (const float*)d_in[0];
    const float* om = (const float*)d_in[1];
    const float* t0 = (const float*)d_in[2];
    const float* t1 = (const float*)d_in[3];
    float* out = (float*)d_out;

    char* ws = (char*)d_ws;
    const size_t xt_bytes = (size_t)NBATCH * PLANE * NCOILS * 2 * sizeof(__half);

    if (ws_size >= (size_t)WS_TOTAL) {
        float4*   xt     = (float4*)(ws + WS_XT);
        float4*   osort  = (float4*)(ws + WS_OSORT);
        unsigned* bhist  = (unsigned*)(ws + WS_BHIST);
        unsigned* btot   = (unsigned*)(ws + WS_BTOT);
        unsigned* bbase  = (unsigned*)(ws + WS_BBASE);
        unsigned* inv    = (unsigned*)(ws + WS_INV);
        float2*   som    = (float2*)(ws + WS_SOM);

        transpose_hist<<<TBLKS + NBLK, 256, 0, stream>>>(x, xt, om, bhist);
        scan_bins<<<NBINS / 16, 1024, 0, stream>>>(bhist, btot);
        scatter2<<<NBLK, 1024, 0, stream>>>(om, bhist, btot, bbase, inv, som);
        interp_bins<<<NBINS, 512, 0, stream>>>(som, t0, t1, xt, bbase, osort);
        unsort_kernel<<<NPTS / 256, 256, 0, stream>>>(inv, osort, out);
    } else if (ws_size >= xt_bytes) {
        float4* xt = (float4*)ws;
        transpose_hist<<<TBLKS, 256, 0, stream>>>(x, xt, om, nullptr);
        interp_direct<<<NPTS * 4 / 256, 256, 0, stream>>>(om, t0, t1, xt, out);
    } else {
        interp_fallback<<<NPTS / 256, 256, 0, stream>>>(om, t0, t1, x, out);
    }
}